// Round 14
// baseline (212.830 us; speedup 1.0000x reference)
//
#include <hip/hip_runtime.h>
#include <math.h>

#define ROWS   8192
#define LQ     4096
#define NHEAD  8
#define NLVL   4
#define NPTS   4
#define HDIM   32

typedef __attribute__((ext_vector_type(8))) short v8s;
typedef __attribute__((ext_vector_type(4))) float v4f;

__device__ __forceinline__ unsigned short f2bf(float x) {
    unsigned int u = __float_as_uint(x);
    u += 0x7fffu + ((u >> 16) & 1u);
    return (unsigned short)(u >> 16);
}
__device__ __forceinline__ float bf2f(unsigned short x) {
    return __uint_as_float(((unsigned int)x) << 16);
}

// async global -> LDS, 16B per lane; LDS dest = wave-uniform base + lane*16
__device__ __forceinline__ void glds16(const void* g, void* l) {
    __builtin_amdgcn_global_load_lds(
        (const __attribute__((address_space(1))) unsigned int*)g,
        (__attribute__((address_space(3))) unsigned int*)l, 16, 0, 0);
}

// ---------------------------------------------------------------------------
// Fused prep: [0,2048) f2bf(src); then 6 transposes; last block biascat.
// ---------------------------------------------------------------------------
__device__ __forceinline__ void trans_tile(const float* __restrict__ in,
                                           unsigned short* __restrict__ out,
                                           int K, int N, int ldout, int n_off,
                                           int bx, int by, int tid)
{
    __shared__ float t[32][33];
    int tx = tid & 31, ty = tid >> 5;           // 32 x 8
    int k0 = by << 5, n0 = bx << 5;
    #pragma unroll
    for (int i = 0; i < 4; i++)
        t[ty + i * 8][tx] = in[(size_t)(k0 + ty + i * 8) * N + n0 + tx];
    __syncthreads();
    #pragma unroll
    for (int i = 0; i < 4; i++)
        out[(size_t)(n_off + n0 + ty + i * 8) * ldout + k0 + tx] = f2bf(t[tx][ty + i * 8]);
}

__global__ __launch_bounds__(256) void prep_k(
    const float* __restrict__ src, unsigned short* __restrict__ src_bf,
    const float* __restrict__ vw, const float* __restrict__ ofw,
    const float* __restrict__ aww, const float* __restrict__ pw,
    const float* __restrict__ w1, const float* __restrict__ w2,
    unsigned short* __restrict__ Btcat, unsigned short* __restrict__ pwT,
    unsigned short* __restrict__ w1T, unsigned short* __restrict__ w2T,
    const float* __restrict__ vb, const float* __restrict__ ofb,
    const float* __restrict__ awb, float* __restrict__ biascat)
{
    int bid = blockIdx.x, tid = threadIdx.x;
    if (bid < 2048) {
        int i = bid * 256 + tid;                 // 524288 float4s
        float4 v = ((const float4*)src)[i];
        ushort4 o;
        o.x = f2bf(v.x); o.y = f2bf(v.y); o.z = f2bf(v.z); o.w = f2bf(v.w);
        ((ushort4*)src_bf)[i] = o;
    } else if (bid < 2112) {                     // vw: 8x8
        int t = bid - 2048; trans_tile(vw, Btcat, 256, 256, 256, 0, t & 7, t >> 3, tid);
    } else if (bid < 2176) {                     // ofw: 8x8
        int t = bid - 2112; trans_tile(ofw, Btcat, 256, 256, 256, 256, t & 7, t >> 3, tid);
    } else if (bid < 2208) {                     // aww: 4x8
        int t = bid - 2176; trans_tile(aww, Btcat, 256, 128, 256, 512, t & 3, t >> 2, tid);
    } else if (bid < 2272) {                     // pw: 8x8
        int t = bid - 2208; trans_tile(pw, pwT, 256, 256, 256, 0, t & 7, t >> 3, tid);
    } else if (bid < 2528) {                     // w1: 32x8
        int t = bid - 2272; trans_tile(w1, w1T, 256, 1024, 256, 0, t & 31, t >> 5, tid);
    } else if (bid < 2784) {                     // w2: 8x32
        int t = bid - 2528; trans_tile(w2, w2T, 1024, 256, 1024, 0, t & 7, t >> 3, tid);
    } else {                                     // biascat
        biascat[tid] = vb[tid];
        biascat[tid + 256] = ofb[tid];
        if (tid < 128) biascat[tid + 512] = awb[tid];
    }
}

// ---------------------------------------------------------------------------
// bf16 MFMA GEMM, BM=128/BN=64/BK=32, glds staging, XOR-swizzled LDS.
// PROJ mode (N=640): cols [0,256) -> compact bf16 value [(b*4+l)*8+h][pix][d];
// cols [256,512) -> out_loc[row][col-256] = refp + v/32 (sampling locations);
// cols [512,640) -> po[row][col-512] fp32 logits.
// ---------------------------------------------------------------------------
template<bool PROJ, bool OUTBF, bool RELU, bool RES>
__global__ __launch_bounds__(256) void mfma_gemm_k(
    const unsigned short* __restrict__ A,   // bf16 [M][K]
    const unsigned short* __restrict__ Bt,  // bf16 [N][K]
    const float* __restrict__ bias,
    const float* __restrict__ res,
    void* __restrict__ Cout,
    unsigned short* __restrict__ vbf,       // PROJ only
    const float* __restrict__ refp,         // PROJ only
    float* __restrict__ oloc,               // PROJ only
    int M, int N, int K)
{
    __shared__ __align__(16) unsigned short As[4096];   // 512 chunks x 16B
    __shared__ __align__(16) unsigned short Bs[2048];   // 256 chunks x 16B
    const int tid = threadIdx.x;
    const int row0 = blockIdx.y << 7, col0 = blockIdx.x << 6;
    const int wid = tid >> 6, lane = tid & 63;
    const int wm = wid & 1, wn = wid >> 1;
    const int lr = lane & 15, kq = lane >> 4;

    v4f acc[4][2];
    #pragma unroll
    for (int i = 0; i < 4; i++)
        #pragma unroll
        for (int j = 0; j < 2; j++) acc[i][j] = (v4f){0.f, 0.f, 0.f, 0.f};

    for (int k0 = 0; k0 < K; k0 += 32) {
        __syncthreads();
        #pragma unroll
        for (int i = 0; i < 2; i++) {
            int c = wid * 128 + i * 64 + lane;
            int row = c >> 2;
            int kk = ((c & 3) + (row >> 2)) & 3;
            glds16(A + (size_t)(row0 + row) * K + k0 + kk * 8,
                   &As[(wid * 128 + i * 64) * 8]);
        }
        {
            int c = wid * 64 + lane;
            int row = c >> 2;
            int kk = ((c & 3) + (row >> 2)) & 3;
            glds16(Bt + (size_t)(col0 + row) * K + k0 + kk * 8,
                   &Bs[wid * 512]);
        }
        __syncthreads();
        v8s bf[2];
        #pragma unroll
        for (int nt = 0; nt < 2; nt++) {
            int row = wn * 32 + nt * 16 + lr;
            int s = (kq - (row >> 2)) & 3;
            bf[nt] = *(const v8s*)(&Bs[(row * 4 + s) * 8]);
        }
        #pragma unroll
        for (int mt = 0; mt < 4; mt++) {
            int row = wm * 64 + mt * 16 + lr;
            int s = (kq - (row >> 2)) & 3;
            v8s af = *(const v8s*)(&As[(row * 4 + s) * 8]);
            #pragma unroll
            for (int nt = 0; nt < 2; nt++)
                acc[mt][nt] = __builtin_amdgcn_mfma_f32_16x16x32_bf16(af, bf[nt], acc[mt][nt], 0, 0, 0);
        }
    }

    const int rq = lane >> 4;
    #pragma unroll
    for (int mt = 0; mt < 4; mt++) {
        #pragma unroll
        for (int nt = 0; nt < 2; nt++) {
            int col = col0 + wn * 32 + nt * 16 + lr;
            float bv = bias[col];
            #pragma unroll
            for (int i = 0; i < 4; i++) {
                int row = row0 + wm * 64 + mt * 16 + rq * 4 + i;
                float v = acc[mt][nt][i] + bv;
                if (RELU) v = fmaxf(v, 0.f);
                if (RES)  v += res[(size_t)row * N + col];
                if (PROJ) {
                    if (col0 < 256) {
                        int b = row >> 12, rb = row & 4095;
                        int l = rb >> 10, pix = rb & 1023;
                        int h = col >> 5, d = col & 31;
                        size_t idx = ((size_t)(((b << 2) + l) * 8 + h) << 15) + (pix << 5) + d;
                        vbf[idx] = f2bf(v);
                    } else if (col0 < 512) {
                        int colm = col - 256;
                        int l = (colm >> 3) & 3, cc = colm & 1;
                        oloc[(size_t)row * 256 + colm] =
                            refp[(size_t)row * 8 + l * 2 + cc] + v * (1.f / 32.f);
                    } else {
                        ((float*)Cout)[(size_t)row * 128 + col - 512] = v;
                    }
                } else if (OUTBF) {
                    ((unsigned short*)Cout)[(size_t)row * N + col] = f2bf(v);
                } else {
                    ((float*)Cout)[(size_t)row * N + col] = v;
                }
            }
        }
    }
}

// ---------------------------------------------------------------------------
// bf16 MFMA GEMM, BM=64/BN=64/BK=32 — N=256 GEMMs, 512 blocks (2/CU).
// ---------------------------------------------------------------------------
template<bool OUTBF, bool RELU, bool RES>
__global__ __launch_bounds__(256) void mfma_gemm64_k(
    const unsigned short* __restrict__ A,   // bf16 [M][K]
    const unsigned short* __restrict__ Bt,  // bf16 [N][K]
    const float* __restrict__ bias,
    const float* __restrict__ res,
    void* __restrict__ Cout,
    int M, int N, int K)
{
    __shared__ __align__(16) unsigned short As[2048];   // 256 chunks x 16B
    __shared__ __align__(16) unsigned short Bs[2048];   // 256 chunks x 16B
    const int tid = threadIdx.x;
    const int row0 = blockIdx.y << 6, col0 = blockIdx.x << 6;
    const int wid = tid >> 6, lane = tid & 63;
    const int lr = lane & 15, kq = lane >> 4;

    v4f acc[4];
    #pragma unroll
    for (int i = 0; i < 4; i++) acc[i] = (v4f){0.f, 0.f, 0.f, 0.f};

    for (int k0 = 0; k0 < K; k0 += 32) {
        __syncthreads();
        {
            int c = wid * 64 + lane;
            int row = c >> 2;
            int kk = ((c & 3) + (row >> 2)) & 3;
            glds16(A + (size_t)(row0 + row) * K + k0 + kk * 8, &As[wid * 512]);
            glds16(Bt + (size_t)(col0 + row) * K + k0 + kk * 8, &Bs[wid * 512]);
        }
        __syncthreads();
        int colr = wid * 16 + lr;
        int sb = (kq - (colr >> 2)) & 3;
        v8s bf = *(const v8s*)(&Bs[(colr * 4 + sb) * 8]);
        #pragma unroll
        for (int mt = 0; mt < 4; mt++) {
            int rowr = mt * 16 + lr;
            int sa = (kq - (rowr >> 2)) & 3;
            v8s af = *(const v8s*)(&As[(rowr * 4 + sa) * 8]);
            acc[mt] = __builtin_amdgcn_mfma_f32_16x16x32_bf16(af, bf, acc[mt], 0, 0, 0);
        }
    }

    const int rq = lane >> 4;
    const int col = col0 + wid * 16 + lr;
    float bv = bias[col];
    #pragma unroll
    for (int mt = 0; mt < 4; mt++) {
        #pragma unroll
        for (int i = 0; i < 4; i++) {
            int row = row0 + mt * 16 + rq * 4 + i;
            float v = acc[mt][i] + bv;
            if (RELU) v = fmaxf(v, 0.f);
            if (RES)  v += res[(size_t)row * N + col];
            if (OUTBF) ((unsigned short*)Cout)[(size_t)row * N + col] = f2bf(v);
            else       ((float*)Cout)[(size_t)row * N + col] = v;
        }
    }
}

// ---------------------------------------------------------------------------
// All-level LDS gather: block = (b, h, 256-row chunk) = 256 blocks (1/CU,
// h = bid&7 XCD-aligned). Double-buffered 64KB sub-tables: prefetch level
// l+1 via glds16 while computing level l from LDS; end-of-level
// __syncthreads drains the prefetch. Accumulate across levels in registers;
// write bf16 attn directly — no fp32 partials, no reduce kernel.
// ---------------------------------------------------------------------------
__global__ __launch_bounds__(256) void gather_lds_k(
    const float* __restrict__ po,            // [ROWS][128] logits
    const unsigned short* __restrict__ vbf,  // [64][1024][32] bf16
    const float* __restrict__ loc,           // [ROWS][256] sampling locs
    unsigned short* __restrict__ attn_bf)    // [ROWS][256] bf16
{
    int bid = blockIdx.x, tid = threadIdx.x;
    int h = bid & 7, rc = (bid >> 3) & 15, b = bid >> 7;

    __shared__ __align__(16) unsigned short vt[2][32768];   // 2 x 64 KB

    const int wv = tid >> 6, lane = tid & 63;
    const unsigned short* vbase_bh = vbf + (((size_t)(b * 4 * 8 + h)) << 15);

    // load level-0 sub-table into buffer 0
    #pragma unroll
    for (int i = 0; i < 16; i++) {
        int base = i * 256 + wv * 64;
        glds16(vbase_bh + (size_t)(base + lane) * 8, &vt[0][base * 8]);
    }

    const int g = tid >> 3, d4 = tid & 7;
    const int rbase = b * 4096 + rc * 256;

    float4 acc8[8];
    #pragma unroll
    for (int i = 0; i < 8; i++) acc8[i] = (float4){0.f, 0.f, 0.f, 0.f};

    for (int l = 0; l < 4; l++) {
        __syncthreads();                       // buffer l&1 ready (drains vm)
        // prefetch next level into the other buffer (overlaps compute)
        if (l < 3) {
            const unsigned short* vnext =
                vbase_bh + (((size_t)((l + 1) * 8)) << 15);
            #pragma unroll
            for (int i = 0; i < 16; i++) {
                int base = i * 256 + wv * 64;
                glds16(vnext + (size_t)(base + lane) * 8, &vt[(l + 1) & 1][base * 8]);
            }
        }
        const unsigned short* vtl = &vt[l & 1][0];

        #pragma unroll 2
        for (int i = 0; i < 8; i++) {
            int r = rbase + g + i * 32;
            // softmax over 16 logits: lane d4 holds logits {2*d4, 2*d4+1}
            float2 lg = *(const float2*)(po + (size_t)r * 128 + h * 16 + d4 * 2);
            float m = fmaxf(lg.x, lg.y);
            m = fmaxf(m, __shfl_xor(m, 1, 8));
            m = fmaxf(m, __shfl_xor(m, 2, 8));
            m = fmaxf(m, __shfl_xor(m, 4, 8));
            float e0 = __expf(lg.x - m), e1 = __expf(lg.y - m);
            float s = e0 + e1;
            s += __shfl_xor(s, 1, 8);
            s += __shfl_xor(s, 2, 8);
            s += __shfl_xor(s, 4, 8);
            float inv = 1.f / s;
            float ww0 = e0 * inv, ww1 = e1 * inv;
            float wgt[4];
            wgt[0] = __shfl(ww0, l * 2, 8);
            wgt[1] = __shfl(ww1, l * 2, 8);
            wgt[2] = __shfl(ww0, l * 2 + 1, 8);
            wgt[3] = __shfl(ww1, l * 2 + 1, 8);

            float locv[8];
            *(float4*)(locv)     = *(const float4*)(loc + (size_t)r * 256 + h * 32 + l * 8);
            *(float4*)(locv + 4) = *(const float4*)(loc + (size_t)r * 256 + h * 32 + l * 8 + 4);

            #pragma unroll
            for (int p = 0; p < 4; p++) {
                float xf = locv[p * 2] * 32.f - 0.5f, yf = locv[p * 2 + 1] * 32.f - 0.5f;
                float x0f = floorf(xf), y0f = floorf(yf);
                float fx = xf - x0f, fy = yf - y0f;
                int x0 = (int)x0f, y0 = (int)y0f;
                #pragma unroll
                for (int dy = 0; dy < 2; dy++) {
                    #pragma unroll
                    for (int dx = 0; dx < 2; dx++) {
                        int xi = x0 + dx, yi = y0 + dy;
                        float wt = (dx ? fx : 1.f - fx) * (dy ? fy : 1.f - fy);
                        bool valid = (xi >= 0) & (xi < 32) & (yi >= 0) & (yi < 32);
                        int xc = min(max(xi, 0), 31), yc = min(max(yi, 0), 31);
                        float c = valid ? (wgt[p] * wt) : 0.f;
                        ushort4 u = *(const ushort4*)(&vtl[((yc << 5) + xc) * 32 + d4 * 4]);
                        acc8[i].x += c * bf2f(u.x); acc8[i].y += c * bf2f(u.y);
                        acc8[i].z += c * bf2f(u.z); acc8[i].w += c * bf2f(u.w);
                    }
                }
            }
        }
    }
    #pragma unroll
    for (int i = 0; i < 8; i++) {
        int r = rbase + g + i * 32;
        ushort4 o;
        o.x = f2bf(acc8[i].x); o.y = f2bf(acc8[i].y);
        o.z = f2bf(acc8[i].z); o.w = f2bf(acc8[i].w);
        *(ushort4*)(attn_bf + (size_t)r * 256 + h * 32 + d4 * 4) = o;
    }
}

// ---------------------------------------------------------------------------
// In-place LayerNorm over 256 cols; optional bf16 copy-out.
// ---------------------------------------------------------------------------
template<bool WRITE_BF>
__global__ __launch_bounds__(256) void layernorm_k(
    float* __restrict__ x, const float* __restrict__ g, const float* __restrict__ b,
    unsigned short* __restrict__ xbf)
{
    int lane = threadIdx.x & 63;
    int wv = threadIdx.x >> 6;
    int row = blockIdx.x * 4 + wv;
    int c = lane << 2;
    float4 v = *(const float4*)(x + (size_t)row * 256 + c);
    float s = v.x + v.y + v.z + v.w;
    #pragma unroll
    for (int o = 1; o < 64; o <<= 1) s += __shfl_xor(s, o);
    float mu = s * (1.f / 256.f);
    float d0 = v.x - mu, d1 = v.y - mu, d2 = v.z - mu, d3 = v.w - mu;
    float vs = d0 * d0 + d1 * d1 + d2 * d2 + d3 * d3;
    #pragma unroll
    for (int o = 1; o < 64; o <<= 1) vs += __shfl_xor(vs, o);
    float rstd = rsqrtf(vs * (1.f / 256.f) + 1e-5f);
    float4 gg = *(const float4*)(g + c);
    float4 bb = *(const float4*)(b + c);
    float4 o4;
    o4.x = d0 * rstd * gg.x + bb.x;
    o4.y = d1 * rstd * gg.y + bb.y;
    o4.z = d2 * rstd * gg.z + bb.z;
    o4.w = d3 * rstd * gg.w + bb.w;
    *(float4*)(x + (size_t)row * 256 + c) = o4;
    if (WRITE_BF) {
        ushort4 ob;
        ob.x = f2bf(o4.x); ob.y = f2bf(o4.y); ob.z = f2bf(o4.z); ob.w = f2bf(o4.w);
        *(ushort4*)(xbf + (size_t)row * 256 + c) = ob;
    }
}

// ---------------------------------------------------------------------------
extern "C" void kernel_launch(void* const* d_in, const int* in_sizes, int n_in,
                              void* d_out, int out_size, void* d_ws, size_t ws_size,
                              hipStream_t stream)
{
    const float* src   = (const float*)d_in[0];
    const float* refp  = (const float*)d_in[2];
    const float* vw    = (const float*)d_in[3];
    const float* vb    = (const float*)d_in[4];
    const float* ofw   = (const float*)d_in[5];
    const float* ofb   = (const float*)d_in[6];
    const float* aww   = (const float*)d_in[7];
    const float* awb   = (const float*)d_in[8];
    const float* pw    = (const float*)d_in[9];
    const float* pb    = (const float*)d_in[10];
    const float* g1    = (const float*)d_in[11];
    const float* b1    = (const float*)d_in[12];
    const float* w1    = (const float*)d_in[13];
    const float* bi1   = (const float*)d_in[14];
    const float* w2    = (const float*)d_in[15];
    const float* bi2   = (const float*)d_in[16];
    const float* g2    = (const float*)d_in[17];
    const float* b2    = (const float*)d_in[18];

    float* ws = (float*)d_ws;
    float*          po        = ws;                               // 1,048,576 f
    float*          x1        = ws + 1048576;                     // 2,097,152 f
    unsigned short* value_bf  = (unsigned short*)(ws + 3145728);  // 2,097,152 us
    unsigned short* src_bf    = (unsigned short*)(ws + 4194304);
    unsigned short* x1_bf     = (unsigned short*)(ws + 5242880);
    unsigned short* attn_bf   = (unsigned short*)(ws + 6291456);
    unsigned short* hidden_bf = (unsigned short*)(ws + 7340032);  // 8,388,608 us
    unsigned short* Btcat     = (unsigned short*)(ws + 11534336); // 163,840 us
    unsigned short* pwT       = (unsigned short*)(ws + 11616256);
    unsigned short* w1T       = (unsigned short*)(ws + 11649024);
    unsigned short* w2T       = (unsigned short*)(ws + 11780096);
    float*          biascat   = ws + 11911168;                    // 640 f

    float* out_x   = (float*)d_out;
    float* out_loc = out_x + 2097152;

    dim3 blk(256);

    // --- all prep in one launch ---
    prep_k<<<2785, blk, 0, stream>>>(src, src_bf, vw, ofw, aww, pw, w1, w2,
                                     Btcat, pwT, w1T, w2T, vb, ofb, awb, biascat);

    // --- fused projections -> value_bf (compact) + out_loc + po logits
    mfma_gemm_k<true, false, false, false><<<dim3(10, 64), blk, 0, stream>>>(
        src_bf, Btcat, biascat, nullptr, po, value_bf, refp, out_loc, ROWS, 640, 256);

    // --- all-level LDS gather -> attn_bf (no partials)
    gather_lds_k<<<256, blk, 0, stream>>>(po, value_bf, out_loc, attn_bf);

    // --- output projection + residual(src) -> x1, LN1 (+bf16 copy)
    mfma_gemm64_k<false, false, true><<<dim3(4, 128), blk, 0, stream>>>(
        attn_bf, pwT, pb, src, x1, ROWS, 256, 256);
    layernorm_k<true><<<2048, blk, 0, stream>>>(x1, g1, b1, x1_bf);

    // --- FFN ---
    mfma_gemm_k<false, true, true, false><<<dim3(16, 64), blk, 0, stream>>>(
        x1_bf, w1T, bi1, nullptr, hidden_bf, nullptr, nullptr, nullptr, ROWS, 1024, 256);
    mfma_gemm64_k<false, false, true><<<dim3(4, 128), blk, 0, stream>>>(
        hidden_bf, w2T, bi2, x1, out_x, ROWS, 256, 1024);
    layernorm_k<false><<<2048, blk, 0, stream>>>(out_x, g2, b2, nullptr);
}

// Round 15
// 188.619 us; speedup vs baseline: 1.1284x; 1.1284x over previous
//
#include <hip/hip_runtime.h>
#include <math.h>

#define ROWS   8192
#define LQ     4096
#define NHEAD  8
#define NLVL   4
#define NPTS   4
#define HDIM   32

typedef __attribute__((ext_vector_type(8))) short v8s;
typedef __attribute__((ext_vector_type(4))) float v4f;

__device__ __forceinline__ unsigned short f2bf(float x) {
    unsigned int u = __float_as_uint(x);
    u += 0x7fffu + ((u >> 16) & 1u);
    return (unsigned short)(u >> 16);
}
__device__ __forceinline__ float bf2f(unsigned short x) {
    return __uint_as_float(((unsigned int)x) << 16);
}

// async global -> LDS, 16B per lane; LDS dest = wave-uniform base + lane*16
__device__ __forceinline__ void glds16(const void* g, void* l) {
    __builtin_amdgcn_global_load_lds(
        (const __attribute__((address_space(1))) unsigned int*)g,
        (__attribute__((address_space(3))) unsigned int*)l, 16, 0, 0);
}

// ---------------------------------------------------------------------------
// Fused prep: [0,2048) f2bf(src); then 6 transposes; last block biascat.
// ---------------------------------------------------------------------------
__device__ __forceinline__ void trans_tile(const float* __restrict__ in,
                                           unsigned short* __restrict__ out,
                                           int K, int N, int ldout, int n_off,
                                           int bx, int by, int tid)
{
    __shared__ float t[32][33];
    int tx = tid & 31, ty = tid >> 5;           // 32 x 8
    int k0 = by << 5, n0 = bx << 5;
    #pragma unroll
    for (int i = 0; i < 4; i++)
        t[ty + i * 8][tx] = in[(size_t)(k0 + ty + i * 8) * N + n0 + tx];
    __syncthreads();
    #pragma unroll
    for (int i = 0; i < 4; i++)
        out[(size_t)(n_off + n0 + ty + i * 8) * ldout + k0 + tx] = f2bf(t[tx][ty + i * 8]);
}

__global__ __launch_bounds__(256) void prep_k(
    const float* __restrict__ src, unsigned short* __restrict__ src_bf,
    const float* __restrict__ vw, const float* __restrict__ ofw,
    const float* __restrict__ aww, const float* __restrict__ pw,
    const float* __restrict__ w1, const float* __restrict__ w2,
    unsigned short* __restrict__ Btcat, unsigned short* __restrict__ pwT,
    unsigned short* __restrict__ w1T, unsigned short* __restrict__ w2T,
    const float* __restrict__ vb, const float* __restrict__ ofb,
    const float* __restrict__ awb, float* __restrict__ biascat)
{
    int bid = blockIdx.x, tid = threadIdx.x;
    if (bid < 2048) {
        int i = bid * 256 + tid;                 // 524288 float4s
        float4 v = ((const float4*)src)[i];
        ushort4 o;
        o.x = f2bf(v.x); o.y = f2bf(v.y); o.z = f2bf(v.z); o.w = f2bf(v.w);
        ((ushort4*)src_bf)[i] = o;
    } else if (bid < 2112) {                     // vw: 8x8
        int t = bid - 2048; trans_tile(vw, Btcat, 256, 256, 256, 0, t & 7, t >> 3, tid);
    } else if (bid < 2176) {                     // ofw: 8x8
        int t = bid - 2112; trans_tile(ofw, Btcat, 256, 256, 256, 256, t & 7, t >> 3, tid);
    } else if (bid < 2208) {                     // aww: 4x8
        int t = bid - 2176; trans_tile(aww, Btcat, 256, 128, 256, 512, t & 3, t >> 2, tid);
    } else if (bid < 2272) {                     // pw: 8x8
        int t = bid - 2208; trans_tile(pw, pwT, 256, 256, 256, 0, t & 7, t >> 3, tid);
    } else if (bid < 2528) {                     // w1: 32x8
        int t = bid - 2272; trans_tile(w1, w1T, 256, 1024, 256, 0, t & 31, t >> 5, tid);
    } else if (bid < 2784) {                     // w2: 8x32
        int t = bid - 2528; trans_tile(w2, w2T, 1024, 256, 1024, 0, t & 7, t >> 3, tid);
    } else {                                     // biascat
        biascat[tid] = vb[tid];
        biascat[tid + 256] = ofb[tid];
        if (tid < 128) biascat[tid + 512] = awb[tid];
    }
}

// ---------------------------------------------------------------------------
// bf16 MFMA GEMM, BM=128/BN=64/BK=32, glds staging, XOR-swizzled LDS.
// PROJ mode (N=640): cols [0,256) -> compact bf16 value [(b*4+l)*8+h][pix][d];
// cols [256,512) -> out_loc[row][col-256] = refp + v/32 (sampling locations);
// cols [512,640) -> po[row][col-512] fp32 logits.
// ---------------------------------------------------------------------------
template<bool PROJ, bool OUTBF, bool RELU, bool RES>
__global__ __launch_bounds__(256) void mfma_gemm_k(
    const unsigned short* __restrict__ A,   // bf16 [M][K]
    const unsigned short* __restrict__ Bt,  // bf16 [N][K]
    const float* __restrict__ bias,
    const float* __restrict__ res,
    void* __restrict__ Cout,
    unsigned short* __restrict__ vbf,       // PROJ only
    const float* __restrict__ refp,         // PROJ only
    float* __restrict__ oloc,               // PROJ only
    int M, int N, int K)
{
    __shared__ __align__(16) unsigned short As[4096];   // 512 chunks x 16B
    __shared__ __align__(16) unsigned short Bs[2048];   // 256 chunks x 16B
    const int tid = threadIdx.x;
    const int row0 = blockIdx.y << 7, col0 = blockIdx.x << 6;
    const int wid = tid >> 6, lane = tid & 63;
    const int wm = wid & 1, wn = wid >> 1;
    const int lr = lane & 15, kq = lane >> 4;

    v4f acc[4][2];
    #pragma unroll
    for (int i = 0; i < 4; i++)
        #pragma unroll
        for (int j = 0; j < 2; j++) acc[i][j] = (v4f){0.f, 0.f, 0.f, 0.f};

    for (int k0 = 0; k0 < K; k0 += 32) {
        __syncthreads();
        #pragma unroll
        for (int i = 0; i < 2; i++) {
            int c = wid * 128 + i * 64 + lane;
            int row = c >> 2;
            int kk = ((c & 3) + (row >> 2)) & 3;
            glds16(A + (size_t)(row0 + row) * K + k0 + kk * 8,
                   &As[(wid * 128 + i * 64) * 8]);
        }
        {
            int c = wid * 64 + lane;
            int row = c >> 2;
            int kk = ((c & 3) + (row >> 2)) & 3;
            glds16(Bt + (size_t)(col0 + row) * K + k0 + kk * 8,
                   &Bs[wid * 512]);
        }
        __syncthreads();
        v8s bf[2];
        #pragma unroll
        for (int nt = 0; nt < 2; nt++) {
            int row = wn * 32 + nt * 16 + lr;
            int s = (kq - (row >> 2)) & 3;
            bf[nt] = *(const v8s*)(&Bs[(row * 4 + s) * 8]);
        }
        #pragma unroll
        for (int mt = 0; mt < 4; mt++) {
            int row = wm * 64 + mt * 16 + lr;
            int s = (kq - (row >> 2)) & 3;
            v8s af = *(const v8s*)(&As[(row * 4 + s) * 8]);
            #pragma unroll
            for (int nt = 0; nt < 2; nt++)
                acc[mt][nt] = __builtin_amdgcn_mfma_f32_16x16x32_bf16(af, bf[nt], acc[mt][nt], 0, 0, 0);
        }
    }

    const int rq = lane >> 4;
    #pragma unroll
    for (int mt = 0; mt < 4; mt++) {
        #pragma unroll
        for (int nt = 0; nt < 2; nt++) {
            int col = col0 + wn * 32 + nt * 16 + lr;
            float bv = bias[col];
            #pragma unroll
            for (int i = 0; i < 4; i++) {
                int row = row0 + wm * 64 + mt * 16 + rq * 4 + i;
                float v = acc[mt][nt][i] + bv;
                if (RELU) v = fmaxf(v, 0.f);
                if (RES)  v += res[(size_t)row * N + col];
                if (PROJ) {
                    if (col0 < 256) {
                        int b = row >> 12, rb = row & 4095;
                        int l = rb >> 10, pix = rb & 1023;
                        int h = col >> 5, d = col & 31;
                        size_t idx = ((size_t)(((b << 2) + l) * 8 + h) << 15) + (pix << 5) + d;
                        vbf[idx] = f2bf(v);
                    } else if (col0 < 512) {
                        int colm = col - 256;
                        int l = (colm >> 3) & 3, cc = colm & 1;
                        oloc[(size_t)row * 256 + colm] =
                            refp[(size_t)row * 8 + l * 2 + cc] + v * (1.f / 32.f);
                    } else {
                        ((float*)Cout)[(size_t)row * 128 + col - 512] = v;
                    }
                } else if (OUTBF) {
                    ((unsigned short*)Cout)[(size_t)row * N + col] = f2bf(v);
                } else {
                    ((float*)Cout)[(size_t)row * N + col] = v;
                }
            }
        }
    }
}

// ---------------------------------------------------------------------------
// bf16 MFMA GEMM, BM=64/BN=64/BK=32 — N=256 GEMMs, 512 blocks (2/CU).
// ---------------------------------------------------------------------------
template<bool OUTBF, bool RELU, bool RES>
__global__ __launch_bounds__(256) void mfma_gemm64_k(
    const unsigned short* __restrict__ A,   // bf16 [M][K]
    const unsigned short* __restrict__ Bt,  // bf16 [N][K]
    const float* __restrict__ bias,
    const float* __restrict__ res,
    void* __restrict__ Cout,
    int M, int N, int K)
{
    __shared__ __align__(16) unsigned short As[2048];   // 256 chunks x 16B
    __shared__ __align__(16) unsigned short Bs[2048];   // 256 chunks x 16B
    const int tid = threadIdx.x;
    const int row0 = blockIdx.y << 6, col0 = blockIdx.x << 6;
    const int wid = tid >> 6, lane = tid & 63;
    const int lr = lane & 15, kq = lane >> 4;

    v4f acc[4];
    #pragma unroll
    for (int i = 0; i < 4; i++) acc[i] = (v4f){0.f, 0.f, 0.f, 0.f};

    for (int k0 = 0; k0 < K; k0 += 32) {
        __syncthreads();
        {
            int c = wid * 64 + lane;
            int row = c >> 2;
            int kk = ((c & 3) + (row >> 2)) & 3;
            glds16(A + (size_t)(row0 + row) * K + k0 + kk * 8, &As[wid * 512]);
            glds16(Bt + (size_t)(col0 + row) * K + k0 + kk * 8, &Bs[wid * 512]);
        }
        __syncthreads();
        int colr = wid * 16 + lr;
        int sb = (kq - (colr >> 2)) & 3;
        v8s bf = *(const v8s*)(&Bs[(colr * 4 + sb) * 8]);
        #pragma unroll
        for (int mt = 0; mt < 4; mt++) {
            int rowr = mt * 16 + lr;
            int sa = (kq - (rowr >> 2)) & 3;
            v8s af = *(const v8s*)(&As[(rowr * 4 + sa) * 8]);
            acc[mt] = __builtin_amdgcn_mfma_f32_16x16x32_bf16(af, bf, acc[mt], 0, 0, 0);
        }
    }

    const int rq = lane >> 4;
    const int col = col0 + wid * 16 + lr;
    float bv = bias[col];
    #pragma unroll
    for (int mt = 0; mt < 4; mt++) {
        #pragma unroll
        for (int i = 0; i < 4; i++) {
            int row = row0 + mt * 16 + rq * 4 + i;
            float v = acc[mt][i] + bv;
            if (RELU) v = fmaxf(v, 0.f);
            if (RES)  v += res[(size_t)row * N + col];
            if (OUTBF) ((unsigned short*)Cout)[(size_t)row * N + col] = f2bf(v);
            else       ((float*)Cout)[(size_t)row * N + col] = v;
        }
    }
}

// ---------------------------------------------------------------------------
// Full-row GEMM + residual + LayerNorm fused epilogue (R11-proven kernel).
// BM=32, BN=256, BK=32; used ONLY for outproj (K=256, B=128KB so the
// per-block B re-read is cheap: 256 blocks x 128KB = 32MB).
// ---------------------------------------------------------------------------
template<bool WRITE_BF>
__global__ __launch_bounds__(256) void mfma_gemm_ln_k(
    const unsigned short* __restrict__ A,   // bf16 [M][K]
    const unsigned short* __restrict__ Bt,  // bf16 [256][K]
    const float* __restrict__ bias,         // [256]
    const float* __restrict__ res,          // [M][256] fp32
    const float* __restrict__ g,
    const float* __restrict__ b,
    float* __restrict__ out,                // [M][256] fp32 post-LN
    unsigned short* __restrict__ outbf,     // optional bf16 post-LN
    int M, int K)
{
    __shared__ __align__(16) unsigned short As[1024];   // 128 chunks x 16B
    __shared__ __align__(16) unsigned short Bs[8192];   // 1024 chunks x 16B
    __shared__ float red[2][32][4];
    const int tid = threadIdx.x;
    const int row0 = blockIdx.x << 5;
    const int wid = tid >> 6, lane = tid & 63;
    const int lr = lane & 15, kq = lane >> 4;
    const int rq = kq;

    v4f acc[2][4];
    #pragma unroll
    for (int i = 0; i < 2; i++)
        #pragma unroll
        for (int j = 0; j < 4; j++) acc[i][j] = (v4f){0.f, 0.f, 0.f, 0.f};

    for (int k0 = 0; k0 < K; k0 += 32) {
        __syncthreads();
        if (wid < 2) {                          // A: 128 chunks
            int c = wid * 64 + lane;
            int row = c >> 2;
            int kk = ((c & 3) + (row >> 2)) & 3;
            glds16(A + (size_t)(row0 + row) * K + k0 + kk * 8,
                   &As[(wid * 64) * 8]);
        }
        #pragma unroll
        for (int i = 0; i < 4; i++) {           // B: 1024 chunks
            int c = (wid * 4 + i) * 64 + lane;
            int col = c >> 2;
            int kk = ((c & 3) + (col >> 2)) & 3;
            glds16(Bt + (size_t)col * K + k0 + kk * 8,
                   &Bs[((wid * 4 + i) * 64) * 8]);
        }
        __syncthreads();
        v8s bf[4];
        #pragma unroll
        for (int ct = 0; ct < 4; ct++) {
            int col = wid * 64 + ct * 16 + lr;
            int s = (kq - (col >> 2)) & 3;
            bf[ct] = *(const v8s*)(&Bs[(col * 4 + s) * 8]);
        }
        #pragma unroll
        for (int rt = 0; rt < 2; rt++) {
            int rowl = rt * 16 + lr;
            int s = (kq - (rowl >> 2)) & 3;
            v8s af = *(const v8s*)(&As[(rowl * 4 + s) * 8]);
            #pragma unroll
            for (int ct = 0; ct < 4; ct++)
                acc[rt][ct] = __builtin_amdgcn_mfma_f32_16x16x32_bf16(af, bf[ct], acc[rt][ct], 0, 0, 0);
        }
    }

    float t[2][4][4];
    float s1[2][4], s2[2][4];
    #pragma unroll
    for (int rt = 0; rt < 2; rt++)
        #pragma unroll
        for (int i = 0; i < 4; i++) { s1[rt][i] = 0.f; s2[rt][i] = 0.f; }
    #pragma unroll
    for (int rt = 0; rt < 2; rt++) {
        #pragma unroll
        for (int ct = 0; ct < 4; ct++) {
            int col = wid * 64 + ct * 16 + lr;
            float bv = bias[col];
            #pragma unroll
            for (int i = 0; i < 4; i++) {
                int row = row0 + rt * 16 + rq * 4 + i;
                float v = acc[rt][ct][i] + bv + res[(size_t)row * 256 + col];
                t[rt][ct][i] = v;
                s1[rt][i] += v;
                s2[rt][i] += v * v;
            }
        }
    }
    #pragma unroll
    for (int o = 1; o < 16; o <<= 1) {
        #pragma unroll
        for (int rt = 0; rt < 2; rt++)
            #pragma unroll
            for (int i = 0; i < 4; i++) {
                s1[rt][i] += __shfl_xor(s1[rt][i], o);
                s2[rt][i] += __shfl_xor(s2[rt][i], o);
            }
    }
    if (lr == 0) {
        #pragma unroll
        for (int rt = 0; rt < 2; rt++)
            #pragma unroll
            for (int i = 0; i < 4; i++) {
                int rl = rt * 16 + rq * 4 + i;
                red[0][rl][wid] = s1[rt][i];
                red[1][rl][wid] = s2[rt][i];
            }
    }
    __syncthreads();
    float mu[2][4], rstd[2][4];
    #pragma unroll
    for (int rt = 0; rt < 2; rt++) {
        #pragma unroll
        for (int i = 0; i < 4; i++) {
            int rl = rt * 16 + rq * 4 + i;
            float S1 = red[0][rl][0] + red[0][rl][1] + red[0][rl][2] + red[0][rl][3];
            float S2 = red[1][rl][0] + red[1][rl][1] + red[1][rl][2] + red[1][rl][3];
            float m = S1 * (1.f / 256.f);
            mu[rt][i] = m;
            rstd[rt][i] = rsqrtf(S2 * (1.f / 256.f) - m * m + 1e-5f);
        }
    }
    #pragma unroll
    for (int rt = 0; rt < 2; rt++) {
        #pragma unroll
        for (int ct = 0; ct < 4; ct++) {
            int col = wid * 64 + ct * 16 + lr;
            float gg = g[col], bb = b[col];
            #pragma unroll
            for (int i = 0; i < 4; i++) {
                int row = row0 + rt * 16 + rq * 4 + i;
                float o = (t[rt][ct][i] - mu[rt][i]) * rstd[rt][i] * gg + bb;
                out[(size_t)row * 256 + col] = o;
                if (WRITE_BF) outbf[(size_t)row * 256 + col] = f2bf(o);
            }
        }
    }
}

// ---------------------------------------------------------------------------
// Fused gather (level-split, XCD-aware h). Loc precomputed by proj epilogue;
// po holds logits only [ROWS][128].  (R10-proven)
// ---------------------------------------------------------------------------
__global__ __launch_bounds__(256) void fused_gather_k(
    const float* __restrict__ po,              // [ROWS][128] logits
    const unsigned short* __restrict__ vbf,    // [64][1024][32] bf16
    const float* __restrict__ loc,             // [ROWS][256] sampling locs
    unsigned short* __restrict__ attn_bf)      // [ROWS][256] bf16
{
    int tid = threadIdx.x;
    int u = tid >> 5, l = (tid >> 3) & 3, d4 = tid & 7;
    int h = blockIdx.x & 7;                    // XCD-aligned head
    int r = (blockIdx.x >> 3) * 8 + u;
    int b = r >> 12;

    float locv[8];
    *(float4*)(locv)     = *(const float4*)(loc + (size_t)r * 256 + h * 32 + l * 8);
    *(float4*)(locv + 4) = *(const float4*)(loc + (size_t)r * 256 + h * 32 + l * 8 + 4);

    float w4[4];
    *(float4*)(w4) = *(const float4*)(po + (size_t)r * 128 + h * 16 + l * 4);
    float m = fmaxf(fmaxf(w4[0], w4[1]), fmaxf(w4[2], w4[3]));
    m = fmaxf(m, __shfl_xor(m, 8));
    m = fmaxf(m, __shfl_xor(m, 16));
    float s = 0.f;
    #pragma unroll
    for (int p = 0; p < 4; p++) { w4[p] = __expf(w4[p] - m); s += w4[p]; }
    s += __shfl_xor(s, 8);
    s += __shfl_xor(s, 16);
    float inv = 1.f / s;

    const unsigned short* vbase =
        vbf + (((size_t)(((b << 2) + l) * 8 + h)) << 15) + d4 * 4;
    ushort4 uv[16];
    float cw[16];
    #pragma unroll
    for (int p = 0; p < 4; p++) {
        float xf = locv[p * 2] * 32.f - 0.5f, yf = locv[p * 2 + 1] * 32.f - 0.5f;
        float x0f = floorf(xf), y0f = floorf(yf);
        float fx = xf - x0f, fy = yf - y0f;
        int x0 = (int)x0f, y0 = (int)y0f;
        float wgt = w4[p] * inv;
        #pragma unroll
        for (int dy = 0; dy < 2; dy++) {
            #pragma unroll
            for (int dx = 0; dx < 2; dx++) {
                int idx = p * 4 + dy * 2 + dx;
                int xi = x0 + dx, yi = y0 + dy;
                float wt = (dx ? fx : 1.f - fx) * (dy ? fy : 1.f - fy);
                bool valid = (xi >= 0) & (xi < 32) & (yi >= 0) & (yi < 32);
                int xc = min(max(xi, 0), 31), yc = min(max(yi, 0), 31);
                cw[idx] = valid ? (wgt * wt) : 0.f;
                uv[idx] = *(const ushort4*)(vbase + (size_t)((yc << 5) + xc) * 32);
            }
        }
    }
    float4 acc = {0.f, 0.f, 0.f, 0.f};
    #pragma unroll
    for (int idx = 0; idx < 16; idx++) {
        float c = cw[idx];
        acc.x += c * bf2f(uv[idx].x); acc.y += c * bf2f(uv[idx].y);
        acc.z += c * bf2f(uv[idx].z); acc.w += c * bf2f(uv[idx].w);
    }
    acc.x += __shfl_xor(acc.x, 8);  acc.y += __shfl_xor(acc.y, 8);
    acc.z += __shfl_xor(acc.z, 8);  acc.w += __shfl_xor(acc.w, 8);
    acc.x += __shfl_xor(acc.x, 16); acc.y += __shfl_xor(acc.y, 16);
    acc.z += __shfl_xor(acc.z, 16); acc.w += __shfl_xor(acc.w, 16);
    if (l == 0) {
        ushort4 o;
        o.x = f2bf(acc.x); o.y = f2bf(acc.y); o.z = f2bf(acc.z); o.w = f2bf(acc.w);
        *(ushort4*)(attn_bf + (size_t)r * 256 + h * 32 + d4 * 4) = o;
    }
}

// ---------------------------------------------------------------------------
// In-place LayerNorm over 256 cols; optional bf16 copy-out.
// ---------------------------------------------------------------------------
template<bool WRITE_BF>
__global__ __launch_bounds__(256) void layernorm_k(
    float* __restrict__ x, const float* __restrict__ g, const float* __restrict__ b,
    unsigned short* __restrict__ xbf)
{
    int lane = threadIdx.x & 63;
    int wv = threadIdx.x >> 6;
    int row = blockIdx.x * 4 + wv;
    int c = lane << 2;
    float4 v = *(const float4*)(x + (size_t)row * 256 + c);
    float s = v.x + v.y + v.z + v.w;
    #pragma unroll
    for (int o = 1; o < 64; o <<= 1) s += __shfl_xor(s, o);
    float mu = s * (1.f / 256.f);
    float d0 = v.x - mu, d1 = v.y - mu, d2 = v.z - mu, d3 = v.w - mu;
    float vs = d0 * d0 + d1 * d1 + d2 * d2 + d3 * d3;
    #pragma unroll
    for (int o = 1; o < 64; o <<= 1) vs += __shfl_xor(vs, o);
    float rstd = rsqrtf(vs * (1.f / 256.f) + 1e-5f);
    float4 gg = *(const float4*)(g + c);
    float4 bb = *(const float4*)(b + c);
    float4 o4;
    o4.x = d0 * rstd * gg.x + bb.x;
    o4.y = d1 * rstd * gg.y + bb.y;
    o4.z = d2 * rstd * gg.z + bb.z;
    o4.w = d3 * rstd * gg.w + bb.w;
    *(float4*)(x + (size_t)row * 256 + c) = o4;
    if (WRITE_BF) {
        ushort4 ob;
        ob.x = f2bf(o4.x); ob.y = f2bf(o4.y); ob.z = f2bf(o4.z); ob.w = f2bf(o4.w);
        *(ushort4*)(xbf + (size_t)row * 256 + c) = ob;
    }
}

// ---------------------------------------------------------------------------
extern "C" void kernel_launch(void* const* d_in, const int* in_sizes, int n_in,
                              void* d_out, int out_size, void* d_ws, size_t ws_size,
                              hipStream_t stream)
{
    const float* src   = (const float*)d_in[0];
    const float* refp  = (const float*)d_in[2];
    const float* vw    = (const float*)d_in[3];
    const float* vb    = (const float*)d_in[4];
    const float* ofw   = (const float*)d_in[5];
    const float* ofb   = (const float*)d_in[6];
    const float* aww   = (const float*)d_in[7];
    const float* awb   = (const float*)d_in[8];
    const float* pw    = (const float*)d_in[9];
    const float* pb    = (const float*)d_in[10];
    const float* g1    = (const float*)d_in[11];
    const float* b1    = (const float*)d_in[12];
    const float* w1    = (const float*)d_in[13];
    const float* bi1   = (const float*)d_in[14];
    const float* w2    = (const float*)d_in[15];
    const float* bi2   = (const float*)d_in[16];
    const float* g2    = (const float*)d_in[17];
    const float* b2    = (const float*)d_in[18];

    float* ws = (float*)d_ws;
    float*          po        = ws;                               // 1,048,576 f
    float*          x1        = ws + 1048576;                     // 2,097,152 f
    unsigned short* value_bf  = (unsigned short*)(ws + 3145728);  // 2,097,152 us
    unsigned short* src_bf    = (unsigned short*)(ws + 4194304);
    unsigned short* x1_bf     = (unsigned short*)(ws + 5242880);
    unsigned short* attn_bf   = (unsigned short*)(ws + 6291456);
    unsigned short* hidden_bf = (unsigned short*)(ws + 7340032);  // 8,388,608 us
    unsigned short* Btcat     = (unsigned short*)(ws + 11534336); // 163,840 us
    unsigned short* pwT       = (unsigned short*)(ws + 11616256);
    unsigned short* w1T       = (unsigned short*)(ws + 11649024);
    unsigned short* w2T       = (unsigned short*)(ws + 11780096);
    float*          biascat   = ws + 11911168;                    // 640 f

    float* out_x   = (float*)d_out;
    float* out_loc = out_x + 2097152;

    dim3 blk(256);

    // --- all prep in one launch ---
    prep_k<<<2785, blk, 0, stream>>>(src, src_bf, vw, ofw, aww, pw, w1, w2,
                                     Btcat, pwT, w1T, w2T, vb, ofb, awb, biascat);

    // --- fused projections -> value_bf (compact) + out_loc + po logits
    mfma_gemm_k<true, false, false, false><<<dim3(10, 64), blk, 0, stream>>>(
        src_bf, Btcat, biascat, nullptr, po, value_bf, refp, out_loc, ROWS, 640, 256);

    // --- softmax + deformable gather -> attn_bf
    fused_gather_k<<<8192, blk, 0, stream>>>(po, value_bf, out_loc, attn_bf);

    // --- output projection + residual(src) + LN1 fused -> x1 (fp32+bf16)
    mfma_gemm_ln_k<true><<<256, blk, 0, stream>>>(
        attn_bf, pwT, pb, src, g1, b1, x1, x1_bf, ROWS, 256);

    // --- FFN1: relu(x1 @ w1 + b1) -> hidden_bf
    mfma_gemm_k<false, true, true, false><<<dim3(16, 64), blk, 0, stream>>>(
        x1_bf, w1T, bi1, nullptr, hidden_bf, nullptr, nullptr, nullptr, ROWS, 1024, 256);

    // --- FFN2 + residual(x1) -> out_x, then LN2
    mfma_gemm64_k<false, false, true><<<dim3(4, 128), blk, 0, stream>>>(
        hidden_bf, w2T, bi2, x1, out_x, ROWS, 256, 1024);
    layernorm_k<false><<<2048, blk, 0, stream>>>(out_x, g2, b2, nullptr);
}

// Round 16
// 182.422 us; speedup vs baseline: 1.1667x; 1.0340x over previous
//
#include <hip/hip_runtime.h>
#include <math.h>

#define ROWS   8192
#define LQ     4096
#define NHEAD  8
#define NLVL   4
#define NPTS   4
#define HDIM   32

typedef __attribute__((ext_vector_type(8))) short v8s;
typedef __attribute__((ext_vector_type(4))) float v4f;
typedef __attribute__((ext_vector_type(8))) unsigned short v8u;

__device__ __forceinline__ unsigned short f2bf(float x) {
    unsigned int u = __float_as_uint(x);
    u += 0x7fffu + ((u >> 16) & 1u);
    return (unsigned short)(u >> 16);
}
__device__ __forceinline__ float bf2f(unsigned short x) {
    return __uint_as_float(((unsigned int)x) << 16);
}

// async global -> LDS, 16B per lane; LDS dest = wave-uniform base + lane*16
__device__ __forceinline__ void glds16(const void* g, void* l) {
    __builtin_amdgcn_global_load_lds(
        (const __attribute__((address_space(1))) unsigned int*)g,
        (__attribute__((address_space(3))) unsigned int*)l, 16, 0, 0);
}

// ---------------------------------------------------------------------------
// Prep: weight transposes + biascat only (src conversion now lives in proj).
// ---------------------------------------------------------------------------
__device__ __forceinline__ void trans_tile(const float* __restrict__ in,
                                           unsigned short* __restrict__ out,
                                           int K, int N, int ldout, int n_off,
                                           int bx, int by, int tid)
{
    __shared__ float t[32][33];
    int tx = tid & 31, ty = tid >> 5;           // 32 x 8
    int k0 = by << 5, n0 = bx << 5;
    #pragma unroll
    for (int i = 0; i < 4; i++)
        t[ty + i * 8][tx] = in[(size_t)(k0 + ty + i * 8) * N + n0 + tx];
    __syncthreads();
    #pragma unroll
    for (int i = 0; i < 4; i++)
        out[(size_t)(n_off + n0 + ty + i * 8) * ldout + k0 + tx] = f2bf(t[tx][ty + i * 8]);
}

__global__ __launch_bounds__(256) void prep_k(
    const float* __restrict__ vw, const float* __restrict__ ofw,
    const float* __restrict__ aww, const float* __restrict__ pw,
    const float* __restrict__ w1, const float* __restrict__ w2,
    unsigned short* __restrict__ Btcat, unsigned short* __restrict__ pwT,
    unsigned short* __restrict__ w1T, unsigned short* __restrict__ w2T,
    const float* __restrict__ vb, const float* __restrict__ ofb,
    const float* __restrict__ awb, float* __restrict__ biascat)
{
    int bid = blockIdx.x, tid = threadIdx.x;
    if (bid < 64) {                              // vw: 8x8
        int t = bid; trans_tile(vw, Btcat, 256, 256, 256, 0, t & 7, t >> 3, tid);
    } else if (bid < 128) {                      // ofw: 8x8
        int t = bid - 64; trans_tile(ofw, Btcat, 256, 256, 256, 256, t & 7, t >> 3, tid);
    } else if (bid < 160) {                      // aww: 4x8
        int t = bid - 128; trans_tile(aww, Btcat, 256, 128, 256, 512, t & 3, t >> 2, tid);
    } else if (bid < 224) {                      // pw: 8x8
        int t = bid - 160; trans_tile(pw, pwT, 256, 256, 256, 0, t & 7, t >> 3, tid);
    } else if (bid < 480) {                      // w1: 32x8
        int t = bid - 224; trans_tile(w1, w1T, 256, 1024, 256, 0, t & 31, t >> 5, tid);
    } else if (bid < 736) {                      // w2: 8x32
        int t = bid - 480; trans_tile(w2, w2T, 1024, 256, 1024, 0, t & 7, t >> 3, tid);
    } else {                                     // biascat
        biascat[tid] = vb[tid];
        biascat[tid + 256] = ofb[tid];
        if (tid < 128) biascat[tid + 512] = awb[tid];
    }
}

// ---------------------------------------------------------------------------
// bf16 MFMA GEMM, BM=128/BN=64/BK=32, XOR-swizzled LDS.
// AF32: A is fp32 in global; staged with in-register f2bf conversion and
// ds_write (replaces the separate conversion pass). Else A via glds16.
// PROJ mode (N=640): cols [0,256) -> compact bf16 value [(b*4+l)*8+h][pix][d];
// cols [256,512) -> out_loc = refp + v/32; cols [512,640) -> po logits.
// ---------------------------------------------------------------------------
template<bool PROJ, bool AF32, bool OUTBF, bool RELU, bool RES>
__global__ __launch_bounds__(256) void mfma_gemm_k(
    const void* __restrict__ Araw,          // bf16 [M][K] or fp32 [M][K]
    const unsigned short* __restrict__ Bt,  // bf16 [N][K]
    const float* __restrict__ bias,
    const float* __restrict__ res,
    void* __restrict__ Cout,
    unsigned short* __restrict__ vbf,       // PROJ only
    const float* __restrict__ refp,         // PROJ only
    float* __restrict__ oloc,               // PROJ only
    int M, int N, int K)
{
    __shared__ __align__(16) unsigned short As[4096];   // 512 chunks x 16B
    __shared__ __align__(16) unsigned short Bs[2048];   // 256 chunks x 16B
    const int tid = threadIdx.x;
    const int row0 = blockIdx.y << 7, col0 = blockIdx.x << 6;
    const int wid = tid >> 6, lane = tid & 63;
    const int wm = wid & 1, wn = wid >> 1;
    const int lr = lane & 15, kq = lane >> 4;

    v4f acc[4][2];
    #pragma unroll
    for (int i = 0; i < 4; i++)
        #pragma unroll
        for (int j = 0; j < 2; j++) acc[i][j] = (v4f){0.f, 0.f, 0.f, 0.f};

    for (int k0 = 0; k0 < K; k0 += 32) {
        float4 af0, af1, af2, af3;
        if constexpr (AF32) {
            const float* Af = (const float*)Araw;
            int r1 = tid >> 2, kk1 = ((tid & 3) + (r1 >> 2)) & 3;
            int c2 = tid + 256;
            int r2 = c2 >> 2, kk2 = ((c2 & 3) + (r2 >> 2)) & 3;
            const float* p1 = Af + (size_t)(row0 + r1) * K + k0 + kk1 * 8;
            const float* p2 = Af + (size_t)(row0 + r2) * K + k0 + kk2 * 8;
            af0 = *(const float4*)p1; af1 = *(const float4*)(p1 + 4);
            af2 = *(const float4*)p2; af3 = *(const float4*)(p2 + 4);
        }
        __syncthreads();
        if constexpr (AF32) {
            v8u u1, u2;
            u1[0] = f2bf(af0.x); u1[1] = f2bf(af0.y); u1[2] = f2bf(af0.z); u1[3] = f2bf(af0.w);
            u1[4] = f2bf(af1.x); u1[5] = f2bf(af1.y); u1[6] = f2bf(af1.z); u1[7] = f2bf(af1.w);
            u2[0] = f2bf(af2.x); u2[1] = f2bf(af2.y); u2[2] = f2bf(af2.z); u2[3] = f2bf(af2.w);
            u2[4] = f2bf(af3.x); u2[5] = f2bf(af3.y); u2[6] = f2bf(af3.z); u2[7] = f2bf(af3.w);
            *(v8u*)(&As[tid * 8]) = u1;
            *(v8u*)(&As[(tid + 256) * 8]) = u2;
        } else {
            const unsigned short* A = (const unsigned short*)Araw;
            #pragma unroll
            for (int i = 0; i < 2; i++) {
                int c = wid * 128 + i * 64 + lane;
                int row = c >> 2;
                int kk = ((c & 3) + (row >> 2)) & 3;
                glds16(A + (size_t)(row0 + row) * K + k0 + kk * 8,
                       &As[(wid * 128 + i * 64) * 8]);
            }
        }
        {
            int c = wid * 64 + lane;
            int row = c >> 2;
            int kk = ((c & 3) + (row >> 2)) & 3;
            glds16(Bt + (size_t)(col0 + row) * K + k0 + kk * 8,
                   &Bs[wid * 512]);
        }
        __syncthreads();
        v8s bf[2];
        #pragma unroll
        for (int nt = 0; nt < 2; nt++) {
            int row = wn * 32 + nt * 16 + lr;
            int s = (kq - (row >> 2)) & 3;
            bf[nt] = *(const v8s*)(&Bs[(row * 4 + s) * 8]);
        }
        #pragma unroll
        for (int mt = 0; mt < 4; mt++) {
            int row = wm * 64 + mt * 16 + lr;
            int s = (kq - (row >> 2)) & 3;
            v8s af = *(const v8s*)(&As[(row * 4 + s) * 8]);
            #pragma unroll
            for (int nt = 0; nt < 2; nt++)
                acc[mt][nt] = __builtin_amdgcn_mfma_f32_16x16x32_bf16(af, bf[nt], acc[mt][nt], 0, 0, 0);
        }
    }

    const int rq = lane >> 4;
    #pragma unroll
    for (int mt = 0; mt < 4; mt++) {
        #pragma unroll
        for (int nt = 0; nt < 2; nt++) {
            int col = col0 + wn * 32 + nt * 16 + lr;
            float bv = bias[col];
            #pragma unroll
            for (int i = 0; i < 4; i++) {
                int row = row0 + wm * 64 + mt * 16 + rq * 4 + i;
                float v = acc[mt][nt][i] + bv;
                if (RELU) v = fmaxf(v, 0.f);
                if (RES)  v += res[(size_t)row * N + col];
                if (PROJ) {
                    if (col0 < 256) {
                        int b = row >> 12, rb = row & 4095;
                        int l = rb >> 10, pix = rb & 1023;
                        int h = col >> 5, d = col & 31;
                        size_t idx = ((size_t)(((b << 2) + l) * 8 + h) << 15) + (pix << 5) + d;
                        vbf[idx] = f2bf(v);
                    } else if (col0 < 512) {
                        int colm = col - 256;
                        int l = (colm >> 3) & 3, cc = colm & 1;
                        oloc[(size_t)row * 256 + colm] =
                            refp[(size_t)row * 8 + l * 2 + cc] + v * (1.f / 32.f);
                    } else {
                        ((float*)Cout)[(size_t)row * 128 + col - 512] = v;
                    }
                } else if (OUTBF) {
                    ((unsigned short*)Cout)[(size_t)row * N + col] = f2bf(v);
                } else {
                    ((float*)Cout)[(size_t)row * N + col] = v;
                }
            }
        }
    }
}

// ---------------------------------------------------------------------------
// bf16 MFMA GEMM, BM=64/BN=64/BK=32 — N=256 GEMMs, 512 blocks (2/CU).
// ---------------------------------------------------------------------------
template<bool OUTBF, bool RELU, bool RES>
__global__ __launch_bounds__(256) void mfma_gemm64_k(
    const unsigned short* __restrict__ A,   // bf16 [M][K]
    const unsigned short* __restrict__ Bt,  // bf16 [N][K]
    const float* __restrict__ bias,
    const float* __restrict__ res,
    void* __restrict__ Cout,
    int M, int N, int K)
{
    __shared__ __align__(16) unsigned short As[2048];   // 256 chunks x 16B
    __shared__ __align__(16) unsigned short Bs[2048];   // 256 chunks x 16B
    const int tid = threadIdx.x;
    const int row0 = blockIdx.y << 6, col0 = blockIdx.x << 6;
    const int wid = tid >> 6, lane = tid & 63;
    const int lr = lane & 15, kq = lane >> 4;

    v4f acc[4];
    #pragma unroll
    for (int i = 0; i < 4; i++) acc[i] = (v4f){0.f, 0.f, 0.f, 0.f};

    for (int k0 = 0; k0 < K; k0 += 32) {
        __syncthreads();
        {
            int c = wid * 64 + lane;
            int row = c >> 2;
            int kk = ((c & 3) + (row >> 2)) & 3;
            glds16(A + (size_t)(row0 + row) * K + k0 + kk * 8, &As[wid * 512]);
            glds16(Bt + (size_t)(col0 + row) * K + k0 + kk * 8, &Bs[wid * 512]);
        }
        __syncthreads();
        int colr = wid * 16 + lr;
        int sb = (kq - (colr >> 2)) & 3;
        v8s bf = *(const v8s*)(&Bs[(colr * 4 + sb) * 8]);
        #pragma unroll
        for (int mt = 0; mt < 4; mt++) {
            int rowr = mt * 16 + lr;
            int sa = (kq - (rowr >> 2)) & 3;
            v8s af = *(const v8s*)(&As[(rowr * 4 + sa) * 8]);
            acc[mt] = __builtin_amdgcn_mfma_f32_16x16x32_bf16(af, bf, acc[mt], 0, 0, 0);
        }
    }

    const int rq = lane >> 4;
    const int col = col0 + wid * 16 + lr;
    float bv = bias[col];
    #pragma unroll
    for (int mt = 0; mt < 4; mt++) {
        #pragma unroll
        for (int i = 0; i < 4; i++) {
            int row = row0 + mt * 16 + rq * 4 + i;
            float v = acc[mt][i] + bv;
            if (RELU) v = fmaxf(v, 0.f);
            if (RES)  v += res[(size_t)row * N + col];
            if (OUTBF) ((unsigned short*)Cout)[(size_t)row * N + col] = f2bf(v);
            else       ((float*)Cout)[(size_t)row * N + col] = v;
        }
    }
}

// ---------------------------------------------------------------------------
// Full-row GEMM + residual + LayerNorm fused epilogue (R15-proven; outproj).
// ---------------------------------------------------------------------------
template<bool WRITE_BF>
__global__ __launch_bounds__(256) void mfma_gemm_ln_k(
    const unsigned short* __restrict__ A,   // bf16 [M][K]
    const unsigned short* __restrict__ Bt,  // bf16 [256][K]
    const float* __restrict__ bias,         // [256]
    const float* __restrict__ res,          // [M][256] fp32
    const float* __restrict__ g,
    const float* __restrict__ b,
    float* __restrict__ out,                // [M][256] fp32 post-LN
    unsigned short* __restrict__ outbf,     // optional bf16 post-LN
    int M, int K)
{
    __shared__ __align__(16) unsigned short As[1024];   // 128 chunks x 16B
    __shared__ __align__(16) unsigned short Bs[8192];   // 1024 chunks x 16B
    __shared__ float red[2][32][4];
    const int tid = threadIdx.x;
    const int row0 = blockIdx.x << 5;
    const int wid = tid >> 6, lane = tid & 63;
    const int lr = lane & 15, kq = lane >> 4;
    const int rq = kq;

    v4f acc[2][4];
    #pragma unroll
    for (int i = 0; i < 2; i++)
        #pragma unroll
        for (int j = 0; j < 4; j++) acc[i][j] = (v4f){0.f, 0.f, 0.f, 0.f};

    for (int k0 = 0; k0 < K; k0 += 32) {
        __syncthreads();
        if (wid < 2) {                          // A: 128 chunks
            int c = wid * 64 + lane;
            int row = c >> 2;
            int kk = ((c & 3) + (row >> 2)) & 3;
            glds16(A + (size_t)(row0 + row) * K + k0 + kk * 8,
                   &As[(wid * 64) * 8]);
        }
        #pragma unroll
        for (int i = 0; i < 4; i++) {           // B: 1024 chunks
            int c = (wid * 4 + i) * 64 + lane;
            int col = c >> 2;
            int kk = ((c & 3) + (col >> 2)) & 3;
            glds16(Bt + (size_t)col * K + k0 + kk * 8,
                   &Bs[((wid * 4 + i) * 64) * 8]);
        }
        __syncthreads();
        v8s bf[4];
        #pragma unroll
        for (int ct = 0; ct < 4; ct++) {
            int col = wid * 64 + ct * 16 + lr;
            int s = (kq - (col >> 2)) & 3;
            bf[ct] = *(const v8s*)(&Bs[(col * 4 + s) * 8]);
        }
        #pragma unroll
        for (int rt = 0; rt < 2; rt++) {
            int rowl = rt * 16 + lr;
            int s = (kq - (rowl >> 2)) & 3;
            v8s af = *(const v8s*)(&As[(rowl * 4 + s) * 8]);
            #pragma unroll
            for (int ct = 0; ct < 4; ct++)
                acc[rt][ct] = __builtin_amdgcn_mfma_f32_16x16x32_bf16(af, bf[ct], acc[rt][ct], 0, 0, 0);
        }
    }

    float t[2][4][4];
    float s1[2][4], s2[2][4];
    #pragma unroll
    for (int rt = 0; rt < 2; rt++)
        #pragma unroll
        for (int i = 0; i < 4; i++) { s1[rt][i] = 0.f; s2[rt][i] = 0.f; }
    #pragma unroll
    for (int rt = 0; rt < 2; rt++) {
        #pragma unroll
        for (int ct = 0; ct < 4; ct++) {
            int col = wid * 64 + ct * 16 + lr;
            float bv = bias[col];
            #pragma unroll
            for (int i = 0; i < 4; i++) {
                int row = row0 + rt * 16 + rq * 4 + i;
                float v = acc[rt][ct][i] + bv + res[(size_t)row * 256 + col];
                t[rt][ct][i] = v;
                s1[rt][i] += v;
                s2[rt][i] += v * v;
            }
        }
    }
    #pragma unroll
    for (int o = 1; o < 16; o <<= 1) {
        #pragma unroll
        for (int rt = 0; rt < 2; rt++)
            #pragma unroll
            for (int i = 0; i < 4; i++) {
                s1[rt][i] += __shfl_xor(s1[rt][i], o);
                s2[rt][i] += __shfl_xor(s2[rt][i], o);
            }
    }
    if (lr == 0) {
        #pragma unroll
        for (int rt = 0; rt < 2; rt++)
            #pragma unroll
            for (int i = 0; i < 4; i++) {
                int rl = rt * 16 + rq * 4 + i;
                red[0][rl][wid] = s1[rt][i];
                red[1][rl][wid] = s2[rt][i];
            }
    }
    __syncthreads();
    float mu[2][4], rstd[2][4];
    #pragma unroll
    for (int rt = 0; rt < 2; rt++) {
        #pragma unroll
        for (int i = 0; i < 4; i++) {
            int rl = rt * 16 + rq * 4 + i;
            float S1 = red[0][rl][0] + red[0][rl][1] + red[0][rl][2] + red[0][rl][3];
            float S2 = red[1][rl][0] + red[1][rl][1] + red[1][rl][2] + red[1][rl][3];
            float m = S1 * (1.f / 256.f);
            mu[rt][i] = m;
            rstd[rt][i] = rsqrtf(S2 * (1.f / 256.f) - m * m + 1e-5f);
        }
    }
    #pragma unroll
    for (int rt = 0; rt < 2; rt++) {
        #pragma unroll
        for (int ct = 0; ct < 4; ct++) {
            int col = wid * 64 + ct * 16 + lr;
            float gg = g[col], bb = b[col];
            #pragma unroll
            for (int i = 0; i < 4; i++) {
                int row = row0 + rt * 16 + rq * 4 + i;
                float o = (t[rt][ct][i] - mu[rt][i]) * rstd[rt][i] * gg + bb;
                out[(size_t)row * 256 + col] = o;
                if (WRITE_BF) outbf[(size_t)row * 256 + col] = f2bf(o);
            }
        }
    }
}

// ---------------------------------------------------------------------------
// Fused gather, level-split with 16B taps: thread = (group g, l, d8); 4 lanes
// x ushort8 per (r,h,l) -> one 64B line per tap, half the VMEM instructions
// of the 8B variant. Softmax/level-reduce via __shfl_xor(4/8). XCD-aware h.
// Grid 4096 blocks (16 (r,h) groups per block).
// ---------------------------------------------------------------------------
__global__ __launch_bounds__(256) void fused_gather_k(
    const float* __restrict__ po,              // [ROWS][128] logits
    const unsigned short* __restrict__ vbf,    // [64][1024][32] bf16
    const float* __restrict__ loc,             // [ROWS][256] sampling locs
    unsigned short* __restrict__ attn_bf)      // [ROWS][256] bf16
{
    int tid = threadIdx.x;
    int g = tid >> 4, l = (tid >> 2) & 3, d8 = tid & 3;
    int h = blockIdx.x & 7;                    // XCD-aligned head
    int r = (blockIdx.x >> 3) * 16 + g;
    int b = r >> 12;

    float locv[8];
    *(float4*)(locv)     = *(const float4*)(loc + (size_t)r * 256 + h * 32 + l * 8);
    *(float4*)(locv + 4) = *(const float4*)(loc + (size_t)r * 256 + h * 32 + l * 8 + 4);

    float w4[4];
    *(float4*)(w4) = *(const float4*)(po + (size_t)r * 128 + h * 16 + l * 4);
    float m = fmaxf(fmaxf(w4[0], w4[1]), fmaxf(w4[2], w4[3]));
    m = fmaxf(m, __shfl_xor(m, 4));
    m = fmaxf(m, __shfl_xor(m, 8));
    float s = 0.f;
    #pragma unroll
    for (int p = 0; p < 4; p++) { w4[p] = __expf(w4[p] - m); s += w4[p]; }
    s += __shfl_xor(s, 4);
    s += __shfl_xor(s, 8);
    float inv = 1.f / s;

    const unsigned short* vbase =
        vbf + (((size_t)(((b << 2) + l) * 8 + h)) << 15) + d8 * 8;

    float acc[8];
    #pragma unroll
    for (int k = 0; k < 8; k++) acc[k] = 0.f;

    #pragma unroll
    for (int pp = 0; pp < 2; pp++) {           // 2 points per batch, 8 taps staged
        v8u uv[8];
        float cw[8];
        #pragma unroll
        for (int p2 = 0; p2 < 2; p2++) {
            int p = pp * 2 + p2;
            float xf = locv[p * 2] * 32.f - 0.5f, yf = locv[p * 2 + 1] * 32.f - 0.5f;
            float x0f = floorf(xf), y0f = floorf(yf);
            float fx = xf - x0f, fy = yf - y0f;
            int x0 = (int)x0f, y0 = (int)y0f;
            float wgt = w4[p] * inv;
            #pragma unroll
            for (int dy = 0; dy < 2; dy++) {
                #pragma unroll
                for (int dx = 0; dx < 2; dx++) {
                    int idx = p2 * 4 + dy * 2 + dx;
                    int xi = x0 + dx, yi = y0 + dy;
                    float wt = (dx ? fx : 1.f - fx) * (dy ? fy : 1.f - fy);
                    bool valid = (xi >= 0) & (xi < 32) & (yi >= 0) & (yi < 32);
                    int xc = min(max(xi, 0), 31), yc = min(max(yi, 0), 31);
                    cw[idx] = valid ? (wgt * wt) : 0.f;
                    uv[idx] = *(const v8u*)(vbase + (size_t)((yc << 5) + xc) * 32);
                }
            }
        }
        #pragma unroll
        for (int idx = 0; idx < 8; idx++) {
            float c = cw[idx];
            #pragma unroll
            for (int k = 0; k < 8; k++)
                acc[k] += c * bf2f(uv[idx][k]);
        }
    }
    // reduce across the 4 level-lanes (strides 4, 8); d8 bits untouched
    #pragma unroll
    for (int k = 0; k < 8; k++) {
        acc[k] += __shfl_xor(acc[k], 4);
        acc[k] += __shfl_xor(acc[k], 8);
    }
    if (l == 0) {
        v8u o;
        #pragma unroll
        for (int k = 0; k < 8; k++) o[k] = f2bf(acc[k]);
        *(v8u*)(attn_bf + (size_t)r * 256 + h * 32 + d8 * 8) = o;
    }
}

// ---------------------------------------------------------------------------
// In-place LayerNorm over 256 cols; optional bf16 copy-out.
// ---------------------------------------------------------------------------
template<bool WRITE_BF>
__global__ __launch_bounds__(256) void layernorm_k(
    float* __restrict__ x, const float* __restrict__ g, const float* __restrict__ b,
    unsigned short* __restrict__ xbf)
{
    int lane = threadIdx.x & 63;
    int wv = threadIdx.x >> 6;
    int row = blockIdx.x * 4 + wv;
    int c = lane << 2;
    float4 v = *(const float4*)(x + (size_t)row * 256 + c);
    float s = v.x + v.y + v.z + v.w;
    #pragma unroll
    for (int o = 1; o < 64; o <<= 1) s += __shfl_xor(s, o);
    float mu = s * (1.f / 256.f);
    float d0 = v.x - mu, d1 = v.y - mu, d2 = v.z - mu, d3 = v.w - mu;
    float vs = d0 * d0 + d1 * d1 + d2 * d2 + d3 * d3;
    #pragma unroll
    for (int o = 1; o < 64; o <<= 1) vs += __shfl_xor(vs, o);
    float rstd = rsqrtf(vs * (1.f / 256.f) + 1e-5f);
    float4 gg = *(const float4*)(g + c);
    float4 bb = *(const float4*)(b + c);
    float4 o4;
    o4.x = d0 * rstd * gg.x + bb.x;
    o4.y = d1 * rstd * gg.y + bb.y;
    o4.z = d2 * rstd * gg.z + bb.z;
    o4.w = d3 * rstd * gg.w + bb.w;
    *(float4*)(x + (size_t)row * 256 + c) = o4;
    if (WRITE_BF) {
        ushort4 ob;
        ob.x = f2bf(o4.x); ob.y = f2bf(o4.y); ob.z = f2bf(o4.z); ob.w = f2bf(o4.w);
        *(ushort4*)(xbf + (size_t)row * 256 + c) = ob;
    }
}

// ---------------------------------------------------------------------------
extern "C" void kernel_launch(void* const* d_in, const int* in_sizes, int n_in,
                              void* d_out, int out_size, void* d_ws, size_t ws_size,
                              hipStream_t stream)
{
    const float* src   = (const float*)d_in[0];
    const float* refp  = (const float*)d_in[2];
    const float* vw    = (const float*)d_in[3];
    const float* vb    = (const float*)d_in[4];
    const float* ofw   = (const float*)d_in[5];
    const float* ofb   = (const float*)d_in[6];
    const float* aww   = (const float*)d_in[7];
    const float* awb   = (const float*)d_in[8];
    const float* pw    = (const float*)d_in[9];
    const float* pb    = (const float*)d_in[10];
    const float* g1    = (const float*)d_in[11];
    const float* b1    = (const float*)d_in[12];
    const float* w1    = (const float*)d_in[13];
    const float* bi1   = (const float*)d_in[14];
    const float* w2    = (const float*)d_in[15];
    const float* bi2   = (const float*)d_in[16];
    const float* g2    = (const float*)d_in[17];
    const float* b2    = (const float*)d_in[18];

    float* ws = (float*)d_ws;
    float*          po        = ws;                               // 1,048,576 f
    float*          x1        = ws + 1048576;                     // 2,097,152 f
    unsigned short* value_bf  = (unsigned short*)(ws + 3145728);  // 2,097,152 us
    unsigned short* x1_bf     = (unsigned short*)(ws + 5242880);
    unsigned short* attn_bf   = (unsigned short*)(ws + 6291456);
    unsigned short* hidden_bf = (unsigned short*)(ws + 7340032);  // 8,388,608 us
    unsigned short* Btcat     = (unsigned short*)(ws + 11534336); // 163,840 us
    unsigned short* pwT       = (unsigned short*)(ws + 11616256);
    unsigned short* w1T       = (unsigned short*)(ws + 11649024);
    unsigned short* w2T       = (unsigned short*)(ws + 11780096);
    float*          biascat   = ws + 11911168;                    // 640 f

    float* out_x   = (float*)d_out;
    float* out_loc = out_x + 2097152;

    dim3 blk(256);

    // --- weight prep (bf16, transposed) + biascat ---
    prep_k<<<737, blk, 0, stream>>>(vw, ofw, aww, pw, w1, w2,
                                    Btcat, pwT, w1T, w2T, vb, ofb, awb, biascat);

    // --- fused projections (A converted in-kernel from fp32 src)
    mfma_gemm_k<true, true, false, false, false><<<dim3(10, 64), blk, 0, stream>>>(
        src, Btcat, biascat, nullptr, po, value_bf, refp, out_loc, ROWS, 640, 256);

    // --- softmax + deformable gather -> attn_bf
    fused_gather_k<<<4096, blk, 0, stream>>>(po, value_bf, out_loc, attn_bf);

    // --- output projection + residual(src) + LN1 fused -> x1 (fp32+bf16)
    mfma_gemm_ln_k<true><<<256, blk, 0, stream>>>(
        attn_bf, pwT, pb, src, g1, b1, x1, x1_bf, ROWS, 256);

    // --- FFN1: relu(x1 @ w1 + b1) -> hidden_bf
    mfma_gemm_k<false, false, true, true, false><<<dim3(16, 64), blk, 0, stream>>>(
        x1_bf, w1T, bi1, nullptr, hidden_bf, nullptr, nullptr, nullptr, ROWS, 1024, 256);

    // --- FFN2 + residual(x1) -> out_x, then LN2
    mfma_gemm64_k<false, false, true><<<dim3(4, 128), blk, 0, stream>>>(
        hidden_bf, w2T, bi2, x1, out_x, ROWS, 256, 1024);
    layernorm_k<false><<<2048, blk, 0, stream>>>(out_x, g2, b2, nullptr);
}

// Round 17
// 181.997 us; speedup vs baseline: 1.1694x; 1.0023x over previous
//
#include <hip/hip_runtime.h>
#include <math.h>

#define ROWS   8192
#define LQ     4096
#define NHEAD  8
#define NLVL   4
#define NPTS   4
#define HDIM   32

typedef __attribute__((ext_vector_type(8))) short v8s;
typedef __attribute__((ext_vector_type(4))) float v4f;
typedef __attribute__((ext_vector_type(8))) unsigned short v8u;

__device__ __forceinline__ unsigned short f2bf(float x) {
    unsigned int u = __float_as_uint(x);
    u += 0x7fffu + ((u >> 16) & 1u);
    return (unsigned short)(u >> 16);
}
__device__ __forceinline__ float bf2f(unsigned short x) {
    return __uint_as_float(((unsigned int)x) << 16);
}

// async global -> LDS, 16B per lane; LDS dest = wave-uniform base + lane*16
__device__ __forceinline__ void glds16(const void* g, void* l) {
    __builtin_amdgcn_global_load_lds(
        (const __attribute__((address_space(1))) unsigned int*)g,
        (__attribute__((address_space(3))) unsigned int*)l, 16, 0, 0);
}

// ---------------------------------------------------------------------------
// Prep: weight transposes + biascat.
// ---------------------------------------------------------------------------
__device__ __forceinline__ void trans_tile(const float* __restrict__ in,
                                           unsigned short* __restrict__ out,
                                           int K, int N, int ldout, int n_off,
                                           int bx, int by, int tid)
{
    __shared__ float t[32][33];
    int tx = tid & 31, ty = tid >> 5;           // 32 x 8
    int k0 = by << 5, n0 = bx << 5;
    #pragma unroll
    for (int i = 0; i < 4; i++)
        t[ty + i * 8][tx] = in[(size_t)(k0 + ty + i * 8) * N + n0 + tx];
    __syncthreads();
    #pragma unroll
    for (int i = 0; i < 4; i++)
        out[(size_t)(n_off + n0 + ty + i * 8) * ldout + k0 + tx] = f2bf(t[tx][ty + i * 8]);
}

__global__ __launch_bounds__(256) void prep_k(
    const float* __restrict__ vw, const float* __restrict__ ofw,
    const float* __restrict__ aww, const float* __restrict__ pw,
    const float* __restrict__ w1, const float* __restrict__ w2,
    unsigned short* __restrict__ Btcat, unsigned short* __restrict__ pwT,
    unsigned short* __restrict__ w1T, unsigned short* __restrict__ w2T,
    const float* __restrict__ vb, const float* __restrict__ ofb,
    const float* __restrict__ awb, float* __restrict__ biascat)
{
    int bid = blockIdx.x, tid = threadIdx.x;
    if (bid < 64) {                              // vw: 8x8
        int t = bid; trans_tile(vw, Btcat, 256, 256, 256, 0, t & 7, t >> 3, tid);
    } else if (bid < 128) {                      // ofw: 8x8
        int t = bid - 64; trans_tile(ofw, Btcat, 256, 256, 256, 256, t & 7, t >> 3, tid);
    } else if (bid < 160) {                      // aww: 4x8
        int t = bid - 128; trans_tile(aww, Btcat, 256, 128, 256, 512, t & 3, t >> 2, tid);
    } else if (bid < 224) {                      // pw: 8x8
        int t = bid - 160; trans_tile(pw, pwT, 256, 256, 256, 0, t & 7, t >> 3, tid);
    } else if (bid < 480) {                      // w1: 32x8
        int t = bid - 224; trans_tile(w1, w1T, 256, 1024, 256, 0, t & 31, t >> 5, tid);
    } else if (bid < 736) {                      // w2: 8x32
        int t = bid - 480; trans_tile(w2, w2T, 1024, 256, 1024, 0, t & 7, t >> 3, tid);
    } else {                                     // biascat
        biascat[tid] = vb[tid];
        biascat[tid + 256] = ofb[tid];
        if (tid < 128) biascat[tid + 512] = awb[tid];
    }
}

// ---------------------------------------------------------------------------
// bf16 MFMA GEMM, BM=64/BN=128/BK=32 — wide-N tile halves the A re-read
// (col-block count) vs BN=64. 4 waves (wm=wid&1 rows, wn=wid>>1 cols);
// wave = 32 rows x 64 cols via 2x4 MFMA tiles. XOR-swizzled glds16 LDS.
// AF32: A fp32 staged with in-register f2bf (1 chunk/thread).
// PROJ (N=640, col0 in {0,128,256,384,512}): [0,256) -> compact value bf16;
// [256,512) -> out_loc = refp + v/32; [512,640) -> po logits.
// ---------------------------------------------------------------------------
template<bool PROJ, bool AF32, bool OUTBF, bool RELU, bool RES>
__global__ __launch_bounds__(256) void mfma_gemm128_k(
    const void* __restrict__ Araw,          // bf16 or fp32 [M][K]
    const unsigned short* __restrict__ Bt,  // bf16 [N][K]
    const float* __restrict__ bias,
    const float* __restrict__ res,
    void* __restrict__ Cout,
    unsigned short* __restrict__ vbf,       // PROJ only
    const float* __restrict__ refp,         // PROJ only
    float* __restrict__ oloc,               // PROJ only
    int M, int N, int K)
{
    __shared__ __align__(16) unsigned short As[2048];   // 256 chunks x 16B
    __shared__ __align__(16) unsigned short Bs[4096];   // 512 chunks x 16B
    const int tid = threadIdx.x;
    const int row0 = blockIdx.y << 6, col0 = blockIdx.x << 7;
    const int wid = tid >> 6, lane = tid & 63;
    const int wm = wid & 1, wn = wid >> 1;
    const int lr = lane & 15, kq = lane >> 4;

    v4f acc[2][4];
    #pragma unroll
    for (int i = 0; i < 2; i++)
        #pragma unroll
        for (int j = 0; j < 4; j++) acc[i][j] = (v4f){0.f, 0.f, 0.f, 0.f};

    for (int k0 = 0; k0 < K; k0 += 32) {
        float4 af0, af1;
        if constexpr (AF32) {
            const float* Af = (const float*)Araw;
            int r1 = tid >> 2, kk1 = ((tid & 3) + (r1 >> 2)) & 3;
            const float* p1 = Af + (size_t)(row0 + r1) * K + k0 + kk1 * 8;
            af0 = *(const float4*)p1; af1 = *(const float4*)(p1 + 4);
        }
        __syncthreads();
        if constexpr (AF32) {
            v8u u1;
            u1[0] = f2bf(af0.x); u1[1] = f2bf(af0.y); u1[2] = f2bf(af0.z); u1[3] = f2bf(af0.w);
            u1[4] = f2bf(af1.x); u1[5] = f2bf(af1.y); u1[6] = f2bf(af1.z); u1[7] = f2bf(af1.w);
            *(v8u*)(&As[tid * 8]) = u1;
        } else {
            const unsigned short* A = (const unsigned short*)Araw;
            int c = wid * 64 + lane;
            int row = c >> 2;
            int kk = ((c & 3) + (row >> 2)) & 3;
            glds16(A + (size_t)(row0 + row) * K + k0 + kk * 8,
                   &As[(wid * 64) * 8]);
        }
        #pragma unroll
        for (int i = 0; i < 2; i++) {
            int c = wid * 128 + i * 64 + lane;
            int row = c >> 2;
            int kk = ((c & 3) + (row >> 2)) & 3;
            glds16(Bt + (size_t)(col0 + row) * K + k0 + kk * 8,
                   &Bs[(wid * 128 + i * 64) * 8]);
        }
        __syncthreads();
        v8s bf[4];
        #pragma unroll
        for (int nt = 0; nt < 4; nt++) {
            int row = wn * 64 + nt * 16 + lr;
            int s = (kq - (row >> 2)) & 3;
            bf[nt] = *(const v8s*)(&Bs[(row * 4 + s) * 8]);
        }
        #pragma unroll
        for (int mt = 0; mt < 2; mt++) {
            int row = wm * 32 + mt * 16 + lr;
            int s = (kq - (row >> 2)) & 3;
            v8s af = *(const v8s*)(&As[(row * 4 + s) * 8]);
            #pragma unroll
            for (int nt = 0; nt < 4; nt++)
                acc[mt][nt] = __builtin_amdgcn_mfma_f32_16x16x32_bf16(af, bf[nt], acc[mt][nt], 0, 0, 0);
        }
    }

    const int rq = lane >> 4;
    #pragma unroll
    for (int mt = 0; mt < 2; mt++) {
        #pragma unroll
        for (int nt = 0; nt < 4; nt++) {
            int col = col0 + wn * 64 + nt * 16 + lr;
            float bv = bias[col];
            #pragma unroll
            for (int i = 0; i < 4; i++) {
                int row = row0 + wm * 32 + mt * 16 + rq * 4 + i;
                float v = acc[mt][nt][i] + bv;
                if (RELU) v = fmaxf(v, 0.f);
                if (RES)  v += res[(size_t)row * N + col];
                if (PROJ) {
                    if (col < 256) {
                        int b = row >> 12, rb = row & 4095;
                        int l = rb >> 10, pix = rb & 1023;
                        int h = col >> 5, d = col & 31;
                        size_t idx = ((size_t)(((b << 2) + l) * 8 + h) << 15) + (pix << 5) + d;
                        vbf[idx] = f2bf(v);
                    } else if (col < 512) {
                        int colm = col - 256;
                        int l = (colm >> 3) & 3, cc = colm & 1;
                        oloc[(size_t)row * 256 + colm] =
                            refp[(size_t)row * 8 + l * 2 + cc] + v * (1.f / 32.f);
                    } else {
                        ((float*)Cout)[(size_t)row * 128 + col - 512] = v;
                    }
                } else if (OUTBF) {
                    ((unsigned short*)Cout)[(size_t)row * N + col] = f2bf(v);
                } else {
                    ((float*)Cout)[(size_t)row * N + col] = v;
                }
            }
        }
    }
}

// ---------------------------------------------------------------------------
// bf16 MFMA GEMM, BM=64/BN=64/BK=32 — FFN2 (N=256), 512 blocks (2/CU).
// ---------------------------------------------------------------------------
template<bool OUTBF, bool RELU, bool RES>
__global__ __launch_bounds__(256) void mfma_gemm64_k(
    const unsigned short* __restrict__ A,   // bf16 [M][K]
    const unsigned short* __restrict__ Bt,  // bf16 [N][K]
    const float* __restrict__ bias,
    const float* __restrict__ res,
    void* __restrict__ Cout,
    int M, int N, int K)
{
    __shared__ __align__(16) unsigned short As[2048];   // 256 chunks x 16B
    __shared__ __align__(16) unsigned short Bs[2048];   // 256 chunks x 16B
    const int tid = threadIdx.x;
    const int row0 = blockIdx.y << 6, col0 = blockIdx.x << 6;
    const int wid = tid >> 6, lane = tid & 63;
    const int lr = lane & 15, kq = lane >> 4;

    v4f acc[4];
    #pragma unroll
    for (int i = 0; i < 4; i++) acc[i] = (v4f){0.f, 0.f, 0.f, 0.f};

    for (int k0 = 0; k0 < K; k0 += 32) {
        __syncthreads();
        {
            int c = wid * 64 + lane;
            int row = c >> 2;
            int kk = ((c & 3) + (row >> 2)) & 3;
            glds16(A + (size_t)(row0 + row) * K + k0 + kk * 8, &As[wid * 512]);
            glds16(Bt + (size_t)(col0 + row) * K + k0 + kk * 8, &Bs[wid * 512]);
        }
        __syncthreads();
        int colr = wid * 16 + lr;
        int sb = (kq - (colr >> 2)) & 3;
        v8s bf = *(const v8s*)(&Bs[(colr * 4 + sb) * 8]);
        #pragma unroll
        for (int mt = 0; mt < 4; mt++) {
            int rowr = mt * 16 + lr;
            int sa = (kq - (rowr >> 2)) & 3;
            v8s af = *(const v8s*)(&As[(rowr * 4 + sa) * 8]);
            acc[mt] = __builtin_amdgcn_mfma_f32_16x16x32_bf16(af, bf, acc[mt], 0, 0, 0);
        }
    }

    const int rq = lane >> 4;
    const int col = col0 + wid * 16 + lr;
    float bv = bias[col];
    #pragma unroll
    for (int mt = 0; mt < 4; mt++) {
        #pragma unroll
        for (int i = 0; i < 4; i++) {
            int row = row0 + mt * 16 + rq * 4 + i;
            float v = acc[mt][i] + bv;
            if (RELU) v = fmaxf(v, 0.f);
            if (RES)  v += res[(size_t)row * N + col];
            if (OUTBF) ((unsigned short*)Cout)[(size_t)row * N + col] = f2bf(v);
            else       ((float*)Cout)[(size_t)row * N + col] = v;
        }
    }
}

// ---------------------------------------------------------------------------
// Full-row GEMM + residual + LayerNorm fused epilogue (outproj; R15-proven).
// ---------------------------------------------------------------------------
template<bool WRITE_BF>
__global__ __launch_bounds__(256) void mfma_gemm_ln_k(
    const unsigned short* __restrict__ A,   // bf16 [M][K]
    const unsigned short* __restrict__ Bt,  // bf16 [256][K]
    const float* __restrict__ bias,         // [256]
    const float* __restrict__ res,          // [M][256] fp32
    const float* __restrict__ g,
    const float* __restrict__ b,
    float* __restrict__ out,                // [M][256] fp32 post-LN
    unsigned short* __restrict__ outbf,     // optional bf16 post-LN
    int M, int K)
{
    __shared__ __align__(16) unsigned short As[1024];   // 128 chunks x 16B
    __shared__ __align__(16) unsigned short Bs[8192];   // 1024 chunks x 16B
    __shared__ float red[2][32][4];
    const int tid = threadIdx.x;
    const int row0 = blockIdx.x << 5;
    const int wid = tid >> 6, lane = tid & 63;
    const int lr = lane & 15, kq = lane >> 4;
    const int rq = kq;

    v4f acc[2][4];
    #pragma unroll
    for (int i = 0; i < 2; i++)
        #pragma unroll
        for (int j = 0; j < 4; j++) acc[i][j] = (v4f){0.f, 0.f, 0.f, 0.f};

    for (int k0 = 0; k0 < K; k0 += 32) {
        __syncthreads();
        if (wid < 2) {                          // A: 128 chunks
            int c = wid * 64 + lane;
            int row = c >> 2;
            int kk = ((c & 3) + (row >> 2)) & 3;
            glds16(A + (size_t)(row0 + row) * K + k0 + kk * 8,
                   &As[(wid * 64) * 8]);
        }
        #pragma unroll
        for (int i = 0; i < 4; i++) {           // B: 1024 chunks
            int c = (wid * 4 + i) * 64 + lane;
            int col = c >> 2;
            int kk = ((c & 3) + (col >> 2)) & 3;
            glds16(Bt + (size_t)col * K + k0 + kk * 8,
                   &Bs[((wid * 4 + i) * 64) * 8]);
        }
        __syncthreads();
        v8s bf[4];
        #pragma unroll
        for (int ct = 0; ct < 4; ct++) {
            int col = wid * 64 + ct * 16 + lr;
            int s = (kq - (col >> 2)) & 3;
            bf[ct] = *(const v8s*)(&Bs[(col * 4 + s) * 8]);
        }
        #pragma unroll
        for (int rt = 0; rt < 2; rt++) {
            int rowl = rt * 16 + lr;
            int s = (kq - (rowl >> 2)) & 3;
            v8s af = *(const v8s*)(&As[(rowl * 4 + s) * 8]);
            #pragma unroll
            for (int ct = 0; ct < 4; ct++)
                acc[rt][ct] = __builtin_amdgcn_mfma_f32_16x16x32_bf16(af, bf[ct], acc[rt][ct], 0, 0, 0);
        }
    }

    float t[2][4][4];
    float s1[2][4], s2[2][4];
    #pragma unroll
    for (int rt = 0; rt < 2; rt++)
        #pragma unroll
        for (int i = 0; i < 4; i++) { s1[rt][i] = 0.f; s2[rt][i] = 0.f; }
    #pragma unroll
    for (int rt = 0; rt < 2; rt++) {
        #pragma unroll
        for (int ct = 0; ct < 4; ct++) {
            int col = wid * 64 + ct * 16 + lr;
            float bv = bias[col];
            #pragma unroll
            for (int i = 0; i < 4; i++) {
                int row = row0 + rt * 16 + rq * 4 + i;
                float v = acc[rt][ct][i] + bv + res[(size_t)row * 256 + col];
                t[rt][ct][i] = v;
                s1[rt][i] += v;
                s2[rt][i] += v * v;
            }
        }
    }
    #pragma unroll
    for (int o = 1; o < 16; o <<= 1) {
        #pragma unroll
        for (int rt = 0; rt < 2; rt++)
            #pragma unroll
            for (int i = 0; i < 4; i++) {
                s1[rt][i] += __shfl_xor(s1[rt][i], o);
                s2[rt][i] += __shfl_xor(s2[rt][i], o);
            }
    }
    if (lr == 0) {
        #pragma unroll
        for (int rt = 0; rt < 2; rt++)
            #pragma unroll
            for (int i = 0; i < 4; i++) {
                int rl = rt * 16 + rq * 4 + i;
                red[0][rl][wid] = s1[rt][i];
                red[1][rl][wid] = s2[rt][i];
            }
    }
    __syncthreads();
    float mu[2][4], rstd[2][4];
    #pragma unroll
    for (int rt = 0; rt < 2; rt++) {
        #pragma unroll
        for (int i = 0; i < 4; i++) {
            int rl = rt * 16 + rq * 4 + i;
            float S1 = red[0][rl][0] + red[0][rl][1] + red[0][rl][2] + red[0][rl][3];
            float S2 = red[1][rl][0] + red[1][rl][1] + red[1][rl][2] + red[1][rl][3];
            float m = S1 * (1.f / 256.f);
            mu[rt][i] = m;
            rstd[rt][i] = rsqrtf(S2 * (1.f / 256.f) - m * m + 1e-5f);
        }
    }
    #pragma unroll
    for (int rt = 0; rt < 2; rt++) {
        #pragma unroll
        for (int ct = 0; ct < 4; ct++) {
            int col = wid * 64 + ct * 16 + lr;
            float gg = g[col], bb = b[col];
            #pragma unroll
            for (int i = 0; i < 4; i++) {
                int row = row0 + rt * 16 + rq * 4 + i;
                float o = (t[rt][ct][i] - mu[rt][i]) * rstd[rt][i] * gg + bb;
                out[(size_t)row * 256 + col] = o;
                if (WRITE_BF) outbf[(size_t)row * 256 + col] = f2bf(o);
            }
        }
    }
}

// ---------------------------------------------------------------------------
// Fused gather, level-split, 16B taps (R16-proven). XCD-aware h.
// ---------------------------------------------------------------------------
__global__ __launch_bounds__(256) void fused_gather_k(
    const float* __restrict__ po,              // [ROWS][128] logits
    const unsigned short* __restrict__ vbf,    // [64][1024][32] bf16
    const float* __restrict__ loc,             // [ROWS][256] sampling locs
    unsigned short* __restrict__ attn_bf)      // [ROWS][256] bf16
{
    int tid = threadIdx.x;
    int g = tid >> 4, l = (tid >> 2) & 3, d8 = tid & 3;
    int h = blockIdx.x & 7;                    // XCD-aligned head
    int r = (blockIdx.x >> 3) * 16 + g;
    int b = r >> 12;

    float locv[8];
    *(float4*)(locv)     = *(const float4*)(loc + (size_t)r * 256 + h * 32 + l * 8);
    *(float4*)(locv + 4) = *(const float4*)(loc + (size_t)r * 256 + h * 32 + l * 8 + 4);

    float w4[4];
    *(float4*)(w4) = *(const float4*)(po + (size_t)r * 128 + h * 16 + l * 4);
    float m = fmaxf(fmaxf(w4[0], w4[1]), fmaxf(w4[2], w4[3]));
    m = fmaxf(m, __shfl_xor(m, 4));
    m = fmaxf(m, __shfl_xor(m, 8));
    float s = 0.f;
    #pragma unroll
    for (int p = 0; p < 4; p++) { w4[p] = __expf(w4[p] - m); s += w4[p]; }
    s += __shfl_xor(s, 4);
    s += __shfl_xor(s, 8);
    float inv = 1.f / s;

    const unsigned short* vbase =
        vbf + (((size_t)(((b << 2) + l) * 8 + h)) << 15) + d8 * 8;

    float acc[8];
    #pragma unroll
    for (int k = 0; k < 8; k++) acc[k] = 0.f;

    #pragma unroll
    for (int pp = 0; pp < 2; pp++) {           // 2 points per batch, 8 taps staged
        v8u uv[8];
        float cw[8];
        #pragma unroll
        for (int p2 = 0; p2 < 2; p2++) {
            int p = pp * 2 + p2;
            float xf = locv[p * 2] * 32.f - 0.5f, yf = locv[p * 2 + 1] * 32.f - 0.5f;
            float x0f = floorf(xf), y0f = floorf(yf);
            float fx = xf - x0f, fy = yf - y0f;
            int x0 = (int)x0f, y0 = (int)y0f;
            float wgt = w4[p] * inv;
            #pragma unroll
            for (int dy = 0; dy < 2; dy++) {
                #pragma unroll
                for (int dx = 0; dx < 2; dx++) {
                    int idx = p2 * 4 + dy * 2 + dx;
                    int xi = x0 + dx, yi = y0 + dy;
                    float wt = (dx ? fx : 1.f - fx) * (dy ? fy : 1.f - fy);
                    bool valid = (xi >= 0) & (xi < 32) & (yi >= 0) & (yi < 32);
                    int xc = min(max(xi, 0), 31), yc = min(max(yi, 0), 31);
                    cw[idx] = valid ? (wgt * wt) : 0.f;
                    uv[idx] = *(const v8u*)(vbase + (size_t)((yc << 5) + xc) * 32);
                }
            }
        }
        #pragma unroll
        for (int idx = 0; idx < 8; idx++) {
            float c = cw[idx];
            #pragma unroll
            for (int k = 0; k < 8; k++)
                acc[k] += c * bf2f(uv[idx][k]);
        }
    }
    #pragma unroll
    for (int k = 0; k < 8; k++) {
        acc[k] += __shfl_xor(acc[k], 4);
        acc[k] += __shfl_xor(acc[k], 8);
    }
    if (l == 0) {
        v8u o;
        #pragma unroll
        for (int k = 0; k < 8; k++) o[k] = f2bf(acc[k]);
        *(v8u*)(attn_bf + (size_t)r * 256 + h * 32 + d8 * 8) = o;
    }
}

// ---------------------------------------------------------------------------
// In-place LayerNorm over 256 cols; optional bf16 copy-out.
// ---------------------------------------------------------------------------
template<bool WRITE_BF>
__global__ __launch_bounds__(256) void layernorm_k(
    float* __restrict__ x, const float* __restrict__ g, const float* __restrict__ b,
    unsigned short* __restrict__ xbf)
{
    int lane = threadIdx.x & 63;
    int wv = threadIdx.x >> 6;
    int row = blockIdx.x * 4 + wv;
    int c = lane << 2;
    float4 v = *(const float4*)(x + (size_t)row * 256 + c);
    float s = v.x + v.y + v.z + v.w;
    #pragma unroll
    for (int o = 1; o < 64; o <<= 1) s += __shfl_xor(s, o);
    float mu = s * (1.f / 256.f);
    float d0 = v.x - mu, d1 = v.y - mu, d2 = v.z - mu, d3 = v.w - mu;
    float vs = d0 * d0 + d1 * d1 + d2 * d2 + d3 * d3;
    #pragma unroll
    for (int o = 1; o < 64; o <<= 1) vs += __shfl_xor(vs, o);
    float rstd = rsqrtf(vs * (1.f / 256.f) + 1e-5f);
    float4 gg = *(const float4*)(g + c);
    float4 bb = *(const float4*)(b + c);
    float4 o4;
    o4.x = d0 * rstd * gg.x + bb.x;
    o4.y = d1 * rstd * gg.y + bb.y;
    o4.z = d2 * rstd * gg.z + bb.z;
    o4.w = d3 * rstd * gg.w + bb.w;
    *(float4*)(x + (size_t)row * 256 + c) = o4;
    if (WRITE_BF) {
        ushort4 ob;
        ob.x = f2bf(o4.x); ob.y = f2bf(o4.y); ob.z = f2bf(o4.z); ob.w = f2bf(o4.w);
        *(ushort4*)(xbf + (size_t)row * 256 + c) = ob;
    }
}

// ---------------------------------------------------------------------------
extern "C" void kernel_launch(void* const* d_in, const int* in_sizes, int n_in,
                              void* d_out, int out_size, void* d_ws, size_t ws_size,
                              hipStream_t stream)
{
    const float* src   = (const float*)d_in[0];
    const float* refp  = (const float*)d_in[2];
    const float* vw    = (const float*)d_in[3];
    const float* vb    = (const float*)d_in[4];
    const float* ofw   = (const float*)d_in[5];
    const float* ofb   = (const float*)d_in[6];
    const float* aww   = (const float*)d_in[7];
    const float* awb   = (const float*)d_in[8];
    const float* pw    = (const float*)d_in[9];
    const float* pb    = (const float*)d_in[10];
    const float* g1    = (const float*)d_in[11];
    const float* b1    = (const float*)d_in[12];
    const float* w1    = (const float*)d_in[13];
    const float* bi1   = (const float*)d_in[14];
    const float* w2    = (const float*)d_in[15];
    const float* bi2   = (const float*)d_in[16];
    const float* g2    = (const float*)d_in[17];
    const float* b2    = (const float*)d_in[18];

    float* ws = (float*)d_ws;
    float*          po        = ws;                               // 1,048,576 f
    float*          x1        = ws + 1048576;                     // 2,097,152 f
    unsigned short* value_bf  = (unsigned short*)(ws + 3145728);  // 2,097,152 us
    unsigned short* x1_bf     = (unsigned short*)(ws + 5242880);
    unsigned short* attn_bf   = (unsigned short*)(ws + 6291456);
    unsigned short* hidden_bf = (unsigned short*)(ws + 7340032);  // 8,388,608 us
    unsigned short* Btcat     = (unsigned short*)(ws + 11534336); // 163,840 us
    unsigned short* pwT       = (unsigned short*)(ws + 11616256);
    unsigned short* w1T       = (unsigned short*)(ws + 11649024);
    unsigned short* w2T       = (unsigned short*)(ws + 11780096);
    float*          biascat   = ws + 11911168;                    // 640 f

    float* out_x   = (float*)d_out;
    float* out_loc = out_x + 2097152;

    dim3 blk(256);

    // --- weight prep (bf16, transposed) + biascat ---
    prep_k<<<737, blk, 0, stream>>>(vw, ofw, aww, pw, w1, w2,
                                    Btcat, pwT, w1T, w2T, vb, ofb, awb, biascat);

    // --- fused projections (A converted in-kernel from fp32 src), BN=128
    mfma_gemm128_k<true, true, false, false, false><<<dim3(5, 128), blk, 0, stream>>>(
        src, Btcat, biascat, nullptr, po, value_bf, refp, out_loc, ROWS, 640, 256);

    // --- softmax + deformable gather -> attn_bf
    fused_gather_k<<<4096, blk, 0, stream>>>(po, value_bf, out_loc, attn_bf);

    // --- output projection + residual(src) + LN1 fused -> x1 (fp32+bf16)
    mfma_gemm_ln_k<true><<<256, blk, 0, stream>>>(
        attn_bf, pwT, pb, src, g1, b1, x1, x1_bf, ROWS, 256);

    // --- FFN1: relu(x1 @ w1 + b1) -> hidden_bf, BN=128
    mfma_gemm128_k<false, false, true, true, false><<<dim3(8, 128), blk, 0, stream>>>(
        x1_bf, w1T, bi1, nullptr, hidden_bf, nullptr, nullptr, nullptr, ROWS, 1024, 256);

    // --- FFN2 + residual(x1) -> out_x, then LN2
    mfma_gemm64_k<false, false, true><<<dim3(4, 128), blk, 0, stream>>>(
        hidden_bf, w2T, bi2, x1, out_x, ROWS, 256, 1024);
    layernorm_k<false><<<2048, blk, 0, stream>>>(out_x, g2, b2, nullptr);
}